// Round 6
// baseline (4337.717 us; speedup 1.0000x reference)
//
#include <hip/hip_runtime.h>
#include <stdint.h>

// Problem constants
#define Bb   128
#define Tt   256
#define Nn   4
#define Dd   64
#define Hh   256
#define G4H  1024          // 4*H
#define MR   64            // episode lanes (rows) per work item

// d_out layout: output (B,T,N,H) | h_n (B,N,L,H) | c_n (B,N,L,H)
#define OUT_HN 33554432    // 128*256*4*256
#define OUT_CN 33816576    // OUT_HN + 128*4*2*256

// workspace byte offsets
#define WS_CTRL 0          // 64 ints: [0]=stride mode, [1]=E, [2]=nchunks, [4..7]=work ctrs
#define WS_HIST 1024       // 257 ints
#define WS_SORT 8192       // 32768 u32 packed episodes (sorted desc by len)
#define WS_BIAS 139264     // N*2*1024 f32 packed bias
#define WS_WPK  262144     // packed bf16 weights: 4 agents * 1664 tiles * 1KB
#define TILES_PER_AGENT 1664   // 64 ntiles * (10 kb L0 + 16 kb L1)

typedef __attribute__((ext_vector_type(4))) float f32x4;
typedef __attribute__((ext_vector_type(8))) short bf16x8;

__device__ __forceinline__ unsigned short f2bf(float f){
  union { float f; unsigned u; } v; v.f = f;
  unsigned r = v.u + 0x7FFFu + ((v.u >> 16) & 1u);  // RNE
  return (unsigned short)(r >> 16);
}
__device__ __forceinline__ float bf2f(short s){
  union { unsigned u; float f; } v; v.u = ((unsigned)(unsigned short)s) << 16;
  return v.f;
}
// fast sigmoid / tanh via v_exp + v_rcp (absmax margin: 0.004 vs 0.0231 threshold)
__device__ __forceinline__ float sigm(float x){
  return __builtin_amdgcn_rcpf(1.f + __expf(-x));
}
__device__ __forceinline__ float tanh_s(float x){
  return 1.f - 2.f * __builtin_amdgcn_rcpf(1.f + __expf(2.f * x));
}

// ---- LDS swizzle helpers (XOR bit4 with row&7 -> conflict-free b128 column reads) ----
__device__ __forceinline__ void st_h(unsigned short* hl, int row, int col, unsigned short v){
  int off = (row * (Hh*2) + col * 2) ^ ((row & 7) << 4);
  *(unsigned short*)((char*)hl + off) = v;
}
__device__ __forceinline__ bf16x8 ld_hfrag(const unsigned short* hl, int m, int kb, int l){
  int row = m*16 + (l & 15);
  int off = (row * (Hh*2) + kb*64 + ((l >> 4) << 4)) ^ ((row & 7) << 4);
  return *(const bf16x8*)((const char*)hl + off);
}
__device__ __forceinline__ bf16x8 ld_xfrag(const unsigned short* xl, int m, int kb, int l){
  int row = m*16 + (l & 15);
  int off = (row * (Dd*2) + kb*64 + ((l >> 4) << 4)) ^ ((row & 7) << 4);
  return *(const bf16x8*)((const char*)xl + off);
}

__device__ __forceinline__ bool get_flag(const unsigned char* p, int t, int stride){
  if (stride == 1) return p[t] != 0;
  return ((const int*)p)[t] != 0;   // covers int32 and f32 bit patterns
}

// ============== prep kernels (merged: 3 dispatches total before k_main) ==============

// detect is_init storage (bool8 vs 4-byte) + per-row episode-length histogram
__global__ void k_prep1(const unsigned char* ii, int* ctrl, int* hist){
  __shared__ int s_cnt;
  __shared__ int s_stride;
  int tid = threadIdx.x;          // 128 threads, one per b
  if (tid == 0) s_cnt = 0;
  __syncthreads();
  atomicAdd(&s_cnt, (ii[2*tid] != 0) + (ii[2*tid+1] != 0));
  __syncthreads();
  if (tid == 0){ s_stride = (s_cnt > 80) ? 1 : 4; ctrl[0] = s_stride; }
  __syncthreads();
  int stride = s_stride;
  const unsigned char* p = ii + (size_t)tid * Tt * stride;
  int start = 0;
  for (int t = 1; t < Tt; t++){
    if (get_flag(p, t, stride)){ atomicAdd(&hist[t - start], 1); start = t; }
  }
  atomicAdd(&hist[Tt - start], 1);
}

// serial scan (thread 0, offs in LDS) + scatter episodes sorted desc by length
__global__ void k_prep2(const unsigned char* ii, int* ctrl, const int* hist,
                        unsigned int* sorted){
  __shared__ int offs_s[Tt + 1];
  int tid = threadIdx.x;          // 128 threads
  if (tid == 0){
    int run = 0;
    for (int len = Tt; len >= 1; len--){ offs_s[len] = run; run += hist[len]; }
    ctrl[1] = run;                     // E
    ctrl[2] = (run + MR - 1) / MR;     // nchunks
  }
  __syncthreads();
  int stride = ctrl[0];
  const unsigned char* p = ii + (size_t)tid * Tt * stride;
  int start = 0;
  for (int t = 1; t < Tt; t++){
    if (get_flag(p, t, stride)){
      int len = t - start;
      int pos = atomicAdd(&offs_s[len], 1);
      sorted[pos] = 0x80000000u | ((unsigned)tid << 16) | ((unsigned)start << 8) | (unsigned)(len - 1);
      start = t;
    }
  }
  int len = Tt - start;
  int pos = atomicAdd(&offs_s[len], 1);
  sorted[pos] = 0x80000000u | ((unsigned)tid << 16) | ((unsigned)start << 8) | (unsigned)(len - 1);
}

// Pack weights to bf16 in exact MFMA fragment order (+ bias pack folded into blocks 0..127).
__global__ void k_packw(const float* __restrict__ Wih0, const float* __restrict__ Whh0,
                        const float* __restrict__ Wih1, const float* __restrict__ Whh1,
                        const float* __restrict__ bih0, const float* __restrict__ bhh0,
                        const float* __restrict__ bih1, const float* __restrict__ bhh1,
                        unsigned short* __restrict__ wpk, float* __restrict__ bpk){
  int bid = blockIdx.x;            // 0..6655
  int l = threadIdx.x;             // 0..63
  int n = bid / TILES_PER_AGENT;
  int r = bid % TILES_PER_AGENT;
  int layer, ntile, kb;
  if (r < 640){ layer = 0; ntile = r / 10; kb = r % 10; }
  else        { layer = 1; r -= 640; ntile = r / 16; kb = r % 16; }
  int col_sub = l >> 2;
  int k8      = (l & 3) * 8;
  int col  = ntile*16 + col_sub;
  int grow = (col & 3)*Hh + (col >> 2);
  const float* src;
  if (layer == 0){
    if (kb < 2) src = Wih0 + ((size_t)(n*G4H + grow))*Dd + kb*32 + k8;        // x part
    else        src = Whh0 + ((size_t)(n*G4H + grow))*Hh + (kb-2)*32 + k8;    // h0 part
  } else {
    if (kb < 8) src = Wih1 + ((size_t)(n*G4H + grow))*Hh + kb*32 + k8;        // h0_new part
    else        src = Whh1 + ((size_t)(n*G4H + grow))*Hh + (kb-8)*32 + k8;    // h1 part
  }
  int tl = (layer == 0) ? (ntile*10 + kb) : (640 + ntile*16 + kb);
  int lp = ((l & 3) << 4) | (l >> 2);
  unsigned short* dst = wpk + (((size_t)n*TILES_PER_AGENT + tl)*64 + lp)*8;
  #pragma unroll
  for (int j = 0; j < 8; j++) dst[j] = f2bf(src[j]);

  // folded bias pack: ids 0..8191 handled by blocks 0..127
  int id = bid*64 + l;
  if (id < Nn*2*G4H){
    int nb = id >> 11; int rb = id & 2047; int lyr = rb >> 10; int c = rb & 1023;
    int gr = (c & 3)*Hh + (c >> 2);
    float v = (lyr == 0) ? (bih0[nb*G4H + gr] + bhh0[nb*G4H + gr])
                         : (bih1[nb*G4H + gr] + bhh1[nb*G4H + gr]);
    bpk[id] = v;
  }
}

// ============== main kernel ==============
// 512 blocks x 512 threads, 2 blocks/CU (LDS 74KB, VGPR capped 128 via
// __launch_bounds__(512,4)). Agent = blockIdx&3 (deterministic, R5).
// OPERAND SWAP: compute mfma(W_frag, x_frag) so D[gatecol][episode]; lane l,
// regs 0..3 = gates i,f,g,o of (episode=l&15, unit_local=l>>4) — the gbuf LDS
// transpose round-trip is an identity and has been deleted. Bias comes from
// global bpk (L2-resident) as f32x4 acc init; biasl LDS buffer deleted.
__launch_bounds__(512, 4)
__global__ void k_main(const float* __restrict__ x_in,
                       const unsigned short* __restrict__ wpk,
                       const float* __restrict__ bpk,
                       const unsigned int* __restrict__ sorted,
                       int* __restrict__ ctrl,
                       float* __restrict__ out)
{
  __shared__ unsigned short h0l[MR*Hh];     // 32KB, swizzled bf16
  __shared__ unsigned short h1l[MR*Hh];     // 32KB
  __shared__ unsigned short xl [MR*Dd];     // 8KB
  __shared__ unsigned int epl[MR];
  __shared__ int item_s;

  const int tid = threadIdx.x;
  const int w   = tid >> 6;
  const int l   = tid & 63;
  const int n   = blockIdx.x & 3;           // deterministic agent assignment
  const int E       = ctrl[1];
  const int nchunks = ctrl[2];

  const unsigned short* wbase = wpk + (size_t)n * TILES_PER_AGENT * 64 * 8;
  const float* bias_g = bpk + n * 2 * G4H;

  const int nrow = l & 15;   // lane's episode row within M-tile
  const int nul  = l >> 4;   // lane's unit_local 0..3

  while (true){
    __syncthreads();
    if (tid == 0) item_s = atomicAdd(&ctrl[4 + n], 1);
    __syncthreads();
    int chunk = item_s;
    if (chunk >= nchunks) break;

    if (tid < MR){
      int idx = chunk*MR + tid;
      epl[tid] = (idx < E) ? sorted[idx] : 0u;
    }
    for (int i = tid; i < MR*Hh/4; i += 512){
      ((ushort4*)h0l)[i] = make_ushort4(0,0,0,0);
      ((ushort4*)h1l)[i] = make_ushort4(0,0,0,0);
    }
    __syncthreads();

    unsigned int ep0 = epl[0];
    int maxlen = (ep0 >> 31) ? (int)(ep0 & 255) + 1 : 0;  // sorted desc -> lane0 is max

    float c0r[8][4], c1r[8][4];
    #pragma unroll
    for (int i = 0; i < 8; i++)
      #pragma unroll
      for (int m = 0; m < 4; m++){ c0r[i][m]=0.f; c1r[i][m]=0.f; }

    #pragma unroll 1
    for (int s = 0; s < maxlen; s++){
      // ---- stage x_t (fp32 -> bf16, swizzled; zeros for finished lanes) ----
      #pragma unroll
      for (int r2 = 0; r2 < 2; r2++){
        int row = r2*32 + (tid >> 4);
        int d4  = (tid & 15) * 4;
        unsigned int pk = epl[row];
        int len = (pk >> 31) ? (int)(pk & 255) + 1 : 0;
        ushort4 u = make_ushort4(0,0,0,0);
        if (s < len){
          int b = (pk >> 16) & 127;
          int t = (int)((pk >> 8) & 255) + s;
          const float* xp = x_in + (((size_t)b*Tt + t)*Nn + n)*Dd + d4;
          f32x4 v = *(const f32x4*)xp;
          u.x = f2bf(v[0]); u.y = f2bf(v[1]); u.z = f2bf(v[2]); u.w = f2bf(v[3]);
        }
        int off = (row*(Dd*2) + d4*2) ^ ((row & 7) << 4);
        *(ushort4*)((char*)xl + off) = u;
      }
      __syncthreads();                                   // bar 1: xl ready

      // ================= LAYER 0 (m-split) =================
      #pragma unroll
      for (int mh = 0; mh < 2; mh++){
        f32x4 acc[8][2];
        #pragma unroll
        for (int i = 0; i < 8; i++){
          f32x4 bv = *(const f32x4*)(bias_g + (w*8 + i)*16 + nul*4);
          acc[i][0] = bv; acc[i][1] = bv;
        }
        for (int kb = 0; kb < 10; kb++){
          bf16x8 a0, a1;
          if (kb < 2){
            a0 = ld_xfrag(xl, mh*2+0, kb, l); a1 = ld_xfrag(xl, mh*2+1, kb, l);
          } else {
            a0 = ld_hfrag(h0l, mh*2+0, kb-2, l); a1 = ld_hfrag(h0l, mh*2+1, kb-2, l);
          }
          #pragma unroll
          for (int i = 0; i < 8; i++){
            const bf16x8 bf = *(const bf16x8*)(wbase + (((size_t)((w*8+i)*10 + kb))*64 + l)*8);
            acc[i][0] = __builtin_amdgcn_mfma_f32_16x16x32_bf16(bf, a0, acc[i][0], 0, 0, 0);
            acc[i][1] = __builtin_amdgcn_mfma_f32_16x16x32_bf16(bf, a1, acc[i][1], 0, 0, 0);
          }
        }
        __syncthreads();   // all waves done reading rows [32mh,32mh+32) (old h0 / x)

        // nonlinearity: gates live in acc regs (swap) — no LDS transpose
        #pragma unroll
        for (int i = 0; i < 8; i++){
          #pragma unroll
          for (int ml = 0; ml < 2; ml++){
            int m = mh*2 + ml;
            f32x4 g = acc[i][ml];
            float cn = sigm(g[1])*c0r[i][m] + sigm(g[0])*tanh_s(g[2]);
            float hn = sigm(g[3])*tanh_s(cn);
            c0r[i][m] = cn;
            int row  = m*16 + nrow;
            int unit = (w*8 + i)*4 + nul;
            st_h(h0l, row, unit, f2bf(hn));
            unsigned int pk = epl[row];
            if (pk >> 31){
              int len = (int)(pk & 255) + 1;
              int start = (pk >> 8) & 255;
              if (s == len - 1 && start + len == Tt){
                int b = (pk >> 16) & 127;
                size_t base = ((size_t)(b*Nn + n)*2 + 0)*Hh + unit;
                __builtin_nontemporal_store(hn, &out[OUT_HN + base]);
                __builtin_nontemporal_store(cn, &out[OUT_CN + base]);
              }
            }
          }
        }
      }
      __syncthreads();   // all h0_new rows visible for layer 1

      // ================= LAYER 1 (m-split) =================
      #pragma unroll
      for (int mh = 0; mh < 2; mh++){
        f32x4 acc[8][2];
        #pragma unroll
        for (int i = 0; i < 8; i++){
          f32x4 bv = *(const f32x4*)(bias_g + G4H + (w*8 + i)*16 + nul*4);
          acc[i][0] = bv; acc[i][1] = bv;
        }
        for (int kb = 0; kb < 16; kb++){
          bf16x8 a0, a1;
          if (kb < 8){
            a0 = ld_hfrag(h0l, mh*2+0, kb, l); a1 = ld_hfrag(h0l, mh*2+1, kb, l);
          } else {
            a0 = ld_hfrag(h1l, mh*2+0, kb-8, l); a1 = ld_hfrag(h1l, mh*2+1, kb-8, l);
          }
          #pragma unroll
          for (int i = 0; i < 8; i++){
            const bf16x8 bf = *(const bf16x8*)(wbase + (((size_t)(640 + (w*8+i)*16 + kb))*64 + l)*8);
            acc[i][0] = __builtin_amdgcn_mfma_f32_16x16x32_bf16(bf, a0, acc[i][0], 0, 0, 0);
            acc[i][1] = __builtin_amdgcn_mfma_f32_16x16x32_bf16(bf, a1, acc[i][1], 0, 0, 0);
          }
        }
        __syncthreads();   // all waves done reading rows [32mh,..) of h0new/h1old

        #pragma unroll
        for (int i = 0; i < 8; i++){
          #pragma unroll
          for (int ml = 0; ml < 2; ml++){
            int m = mh*2 + ml;
            f32x4 g = acc[i][ml];
            float cn = sigm(g[1])*c1r[i][m] + sigm(g[0])*tanh_s(g[2]);
            float hn = sigm(g[3])*tanh_s(cn);
            c1r[i][m] = cn;
            int row  = m*16 + nrow;
            int unit = (w*8 + i)*4 + nul;
            st_h(h1l, row, unit, f2bf(hn));
            unsigned int pk = epl[row];
            if (pk >> 31){
              int len = (int)(pk & 255) + 1;
              int start = (pk >> 8) & 255;
              if (s == len - 1 && start + len == Tt){
                int b = (pk >> 16) & 127;
                size_t base = ((size_t)(b*Nn + n)*2 + 1)*Hh + unit;
                __builtin_nontemporal_store(hn, &out[OUT_HN + base]);
                __builtin_nontemporal_store(cn, &out[OUT_CN + base]);
              }
            }
          }
        }
      }
      __syncthreads();   // h1_new visible for output read

      // ---- output write: output[b, t, n, :] = h1_new (256B segments, NT) ----
      #pragma unroll
      for (int r2 = 0; r2 < 2; r2++){
        int row = r2*32 + (tid >> 4);
        unsigned int pk = epl[row];
        int len = (pk >> 31) ? (int)(pk & 255) + 1 : 0;
        if (s < len){
          int b = (pk >> 16) & 127;
          int t = (int)((pk >> 8) & 255) + s;
          int l16 = tid & 15;
          int swz = (row & 7) << 4;
          float* op = out + (((size_t)b*Tt + t)*Nn + n)*Hh;
          #pragma unroll
          for (int k = 0; k < 4; k++){
            int off = (row*(Hh*2) + k*128 + l16*8) ^ swz;
            ushort4 u = *(const ushort4*)((const char*)h1l + off);
            f32x4 v = { bf2f((short)u.x), bf2f((short)u.y), bf2f((short)u.z), bf2f((short)u.w) };
            __builtin_nontemporal_store(v, (f32x4*)(op + k*64 + l16*4));
          }
        }
      }
      // no trailing barrier needed: next writers of h1l are >=2 barriers away
    } // s loop
  } // work loop
}

// ============== launch ==============
extern "C" void kernel_launch(void* const* d_in, const int* in_sizes, int n_in,
                              void* d_out, int out_size, void* d_ws, size_t ws_size,
                              hipStream_t stream)
{
  const float* x    = (const float*)d_in[0];
  const unsigned char* ii = (const unsigned char*)d_in[1];
  const float* Wih0 = (const float*)d_in[2];
  const float* Whh0 = (const float*)d_in[3];
  const float* bih0 = (const float*)d_in[4];
  const float* bhh0 = (const float*)d_in[5];
  const float* Wih1 = (const float*)d_in[6];
  const float* Whh1 = (const float*)d_in[7];
  const float* bih1 = (const float*)d_in[8];
  const float* bhh1 = (const float*)d_in[9];
  float* out = (float*)d_out;
  char* ws = (char*)d_ws;

  int* ctrl = (int*)(ws + WS_CTRL);
  int* hist = (int*)(ws + WS_HIST);
  unsigned int* sorted = (unsigned int*)(ws + WS_SORT);
  float* bpk = (float*)(ws + WS_BIAS);
  unsigned short* wpkp = (unsigned short*)(ws + WS_WPK);

  hipMemsetAsync(d_ws, 0, 8192, stream);
  k_prep1 <<<1, 128, 0, stream>>>(ii, ctrl, hist);
  k_prep2 <<<1, 128, 0, stream>>>(ii, ctrl, hist, sorted);
  k_packw <<<Nn*TILES_PER_AGENT, 64, 0, stream>>>(Wih0, Whh0, Wih1, Whh1,
                                                  bih0, bhh0, bih1, bhh1, wpkp, bpk);
  k_main  <<<512, 512, 0, stream>>>(x, wpkp, bpk, sorted, ctrl, out);
}

// Round 7
// 3541.130 us; speedup vs baseline: 1.2250x; 1.2250x over previous
//
#include <hip/hip_runtime.h>
#include <stdint.h>

// Problem constants
#define Bb   128
#define Tt   256
#define Nn   4
#define Dd   64
#define Hh   256
#define G4H  1024          // 4*H
#define MR   64            // episode lanes (rows) per work item

// d_out layout: output (B,T,N,H) | h_n (B,N,L,H) | c_n (B,N,L,H)
#define OUT_HN 33554432    // 128*256*4*256
#define OUT_CN 33816576    // OUT_HN + 128*4*2*256

// workspace byte offsets
#define WS_CTRL 0          // 64 ints: [0]=stride mode, [1]=E, [2]=nchunks, [4..7]=work ctrs
#define WS_HIST 1024       // 257 ints
#define WS_SORT 8192       // 32768 u32 packed episodes (sorted desc by len)
#define WS_BIAS 139264     // N*2*1024 f32 packed bias
#define WS_WPK  262144     // packed bf16 weights: 4 agents * 1664 tiles * 1KB
#define TILES_PER_AGENT 1664   // 64 ntiles * (10 kb L0 + 16 kb L1)

typedef __attribute__((ext_vector_type(4))) float f32x4;
typedef __attribute__((ext_vector_type(8))) short bf16x8;

__device__ __forceinline__ unsigned short f2bf(float f){
  union { float f; unsigned u; } v; v.f = f;
  unsigned r = v.u + 0x7FFFu + ((v.u >> 16) & 1u);  // RNE
  return (unsigned short)(r >> 16);
}
__device__ __forceinline__ float bf2f(short s){
  union { unsigned u; float f; } v; v.u = ((unsigned)(unsigned short)s) << 16;
  return v.f;
}
// fast sigmoid / tanh via v_exp + v_rcp (absmax margin: 0.004 vs 0.0231 threshold)
__device__ __forceinline__ float sigm(float x){
  return __builtin_amdgcn_rcpf(1.f + __expf(-x));
}
__device__ __forceinline__ float tanh_s(float x){
  return 1.f - 2.f * __builtin_amdgcn_rcpf(1.f + __expf(2.f * x));
}

// ---- LDS swizzle helpers (XOR bit4 with row&7 -> conflict-free b128 column reads) ----
__device__ __forceinline__ void st_h(unsigned short* hl, int row, int col, unsigned short v){
  int off = (row * (Hh*2) + col * 2) ^ ((row & 7) << 4);
  *(unsigned short*)((char*)hl + off) = v;
}
__device__ __forceinline__ bf16x8 ld_hfrag(const unsigned short* hl, int m, int kb, int l){
  int row = m*16 + (l & 15);
  int off = (row * (Hh*2) + kb*64 + ((l >> 4) << 4)) ^ ((row & 7) << 4);
  return *(const bf16x8*)((const char*)hl + off);
}
__device__ __forceinline__ bf16x8 ld_xfrag(const unsigned short* xl, int m, int kb, int l){
  int row = m*16 + (l & 15);
  int off = (row * (Dd*2) + kb*64 + ((l >> 4) << 4)) ^ ((row & 7) << 4);
  return *(const bf16x8*)((const char*)xl + off);
}

__device__ __forceinline__ bool get_flag(const unsigned char* p, int t, int stride){
  if (stride == 1) return p[t] != 0;
  return ((const int*)p)[t] != 0;   // covers int32 and f32 bit patterns
}

// ============== prep kernels (merged: 3 dispatches total before k_main) ==============

// detect is_init storage (bool8 vs 4-byte) + per-row episode-length histogram
__global__ void k_prep1(const unsigned char* ii, int* ctrl, int* hist){
  __shared__ int s_cnt;
  __shared__ int s_stride;
  int tid = threadIdx.x;          // 128 threads, one per b
  if (tid == 0) s_cnt = 0;
  __syncthreads();
  atomicAdd(&s_cnt, (ii[2*tid] != 0) + (ii[2*tid+1] != 0));
  __syncthreads();
  if (tid == 0){ s_stride = (s_cnt > 80) ? 1 : 4; ctrl[0] = s_stride; }
  __syncthreads();
  int stride = s_stride;
  const unsigned char* p = ii + (size_t)tid * Tt * stride;
  int start = 0;
  for (int t = 1; t < Tt; t++){
    if (get_flag(p, t, stride)){ atomicAdd(&hist[t - start], 1); start = t; }
  }
  atomicAdd(&hist[Tt - start], 1);
}

// serial scan (thread 0, offs in LDS) + scatter episodes sorted desc by length
__global__ void k_prep2(const unsigned char* ii, int* ctrl, const int* hist,
                        unsigned int* sorted){
  __shared__ int offs_s[Tt + 1];
  int tid = threadIdx.x;          // 128 threads
  if (tid == 0){
    int run = 0;
    for (int len = Tt; len >= 1; len--){ offs_s[len] = run; run += hist[len]; }
    ctrl[1] = run;                     // E
    ctrl[2] = (run + MR - 1) / MR;     // nchunks
  }
  __syncthreads();
  int stride = ctrl[0];
  const unsigned char* p = ii + (size_t)tid * Tt * stride;
  int start = 0;
  for (int t = 1; t < Tt; t++){
    if (get_flag(p, t, stride)){
      int len = t - start;
      int pos = atomicAdd(&offs_s[len], 1);
      sorted[pos] = 0x80000000u | ((unsigned)tid << 16) | ((unsigned)start << 8) | (unsigned)(len - 1);
      start = t;
    }
  }
  int len = Tt - start;
  int pos = atomicAdd(&offs_s[len], 1);
  sorted[pos] = 0x80000000u | ((unsigned)tid << 16) | ((unsigned)start << 8) | (unsigned)(len - 1);
}

// Pack weights to bf16 in exact MFMA fragment order (+ bias pack folded into blocks 0..127).
__global__ void k_packw(const float* __restrict__ Wih0, const float* __restrict__ Whh0,
                        const float* __restrict__ Wih1, const float* __restrict__ Whh1,
                        const float* __restrict__ bih0, const float* __restrict__ bhh0,
                        const float* __restrict__ bih1, const float* __restrict__ bhh1,
                        unsigned short* __restrict__ wpk, float* __restrict__ bpk){
  int bid = blockIdx.x;            // 0..6655
  int l = threadIdx.x;             // 0..63
  int n = bid / TILES_PER_AGENT;
  int r = bid % TILES_PER_AGENT;
  int layer, ntile, kb;
  if (r < 640){ layer = 0; ntile = r / 10; kb = r % 10; }
  else        { layer = 1; r -= 640; ntile = r / 16; kb = r % 16; }
  int col_sub = l >> 2;
  int k8      = (l & 3) * 8;
  int col  = ntile*16 + col_sub;
  int grow = (col & 3)*Hh + (col >> 2);
  const float* src;
  if (layer == 0){
    if (kb < 2) src = Wih0 + ((size_t)(n*G4H + grow))*Dd + kb*32 + k8;        // x part
    else        src = Whh0 + ((size_t)(n*G4H + grow))*Hh + (kb-2)*32 + k8;    // h0 part
  } else {
    if (kb < 8) src = Wih1 + ((size_t)(n*G4H + grow))*Hh + kb*32 + k8;        // h0_new part
    else        src = Whh1 + ((size_t)(n*G4H + grow))*Hh + (kb-8)*32 + k8;    // h1 part
  }
  int tl = (layer == 0) ? (ntile*10 + kb) : (640 + ntile*16 + kb);
  int lp = ((l & 3) << 4) | (l >> 2);
  unsigned short* dst = wpk + (((size_t)n*TILES_PER_AGENT + tl)*64 + lp)*8;
  #pragma unroll
  for (int j = 0; j < 8; j++) dst[j] = f2bf(src[j]);

  // folded bias pack: ids 0..8191 handled by blocks 0..127
  int id = bid*64 + l;
  if (id < Nn*2*G4H){
    int nb = id >> 11; int rb = id & 2047; int lyr = rb >> 10; int c = rb & 1023;
    int gr = (c & 3)*Hh + (c >> 2);
    float v = (lyr == 0) ? (bih0[nb*G4H + gr] + bhh0[nb*G4H + gr])
                         : (bih1[nb*G4H + gr] + bhh1[nb*G4H + gr]);
    bpk[id] = v;
  }
}

// ============== main kernel ==============
// 512 blocks x 512 threads. __launch_bounds__(512,2) -> empirically 2 blocks/CU,
// 16 waves/CU, VGPR cap 128 (R5 proved this structure fits 128 with ZERO spill;
// R6's (512,4) forced cap 64 -> massive scratch spill, 4x regression).
// Agent = blockIdx&3 (deterministic, R5). OPERAND SWAP kept from R6:
// mfma(W_frag, x_frag) lands gates i,f,g,o of (episode=l&15, unit=l>>4) directly
// in acc regs 0..3 — no LDS transpose. Bias from global bpk (L2-resident).
__launch_bounds__(512, 2)
__global__ void k_main(const float* __restrict__ x_in,
                       const unsigned short* __restrict__ wpk,
                       const float* __restrict__ bpk,
                       const unsigned int* __restrict__ sorted,
                       int* __restrict__ ctrl,
                       float* __restrict__ out)
{
  __shared__ unsigned short h0l[MR*Hh];     // 32KB, swizzled bf16
  __shared__ unsigned short h1l[MR*Hh];     // 32KB
  __shared__ unsigned short xl [MR*Dd];     // 8KB
  __shared__ unsigned int epl[MR];
  __shared__ int item_s;

  const int tid = threadIdx.x;
  const int w   = tid >> 6;
  const int l   = tid & 63;
  const int n   = blockIdx.x & 3;           // deterministic agent assignment
  const int E       = ctrl[1];
  const int nchunks = ctrl[2];

  const unsigned short* wbase = wpk + (size_t)n * TILES_PER_AGENT * 64 * 8;
  const float* bias_g = bpk + n * 2 * G4H;

  const int nrow = l & 15;   // lane's episode row within M-tile
  const int nul  = l >> 4;   // lane's unit_local 0..3

  while (true){
    __syncthreads();
    if (tid == 0) item_s = atomicAdd(&ctrl[4 + n], 1);
    __syncthreads();
    int chunk = item_s;
    if (chunk >= nchunks) break;

    if (tid < MR){
      int idx = chunk*MR + tid;
      epl[tid] = (idx < E) ? sorted[idx] : 0u;
    }
    for (int i = tid; i < MR*Hh/4; i += 512){
      ((ushort4*)h0l)[i] = make_ushort4(0,0,0,0);
      ((ushort4*)h1l)[i] = make_ushort4(0,0,0,0);
    }
    __syncthreads();

    unsigned int ep0 = epl[0];
    int maxlen = (ep0 >> 31) ? (int)(ep0 & 255) + 1 : 0;  // sorted desc -> lane0 is max

    float c0r[8][4], c1r[8][4];
    #pragma unroll
    for (int i = 0; i < 8; i++)
      #pragma unroll
      for (int m = 0; m < 4; m++){ c0r[i][m]=0.f; c1r[i][m]=0.f; }

    #pragma unroll 1
    for (int s = 0; s < maxlen; s++){
      // ---- stage x_t (fp32 -> bf16, swizzled; zeros for finished lanes) ----
      #pragma unroll
      for (int r2 = 0; r2 < 2; r2++){
        int row = r2*32 + (tid >> 4);
        int d4  = (tid & 15) * 4;
        unsigned int pk = epl[row];
        int len = (pk >> 31) ? (int)(pk & 255) + 1 : 0;
        ushort4 u = make_ushort4(0,0,0,0);
        if (s < len){
          int b = (pk >> 16) & 127;
          int t = (int)((pk >> 8) & 255) + s;
          const float* xp = x_in + (((size_t)b*Tt + t)*Nn + n)*Dd + d4;
          f32x4 v = *(const f32x4*)xp;
          u.x = f2bf(v[0]); u.y = f2bf(v[1]); u.z = f2bf(v[2]); u.w = f2bf(v[3]);
        }
        int off = (row*(Dd*2) + d4*2) ^ ((row & 7) << 4);
        *(ushort4*)((char*)xl + off) = u;
      }
      __syncthreads();                                   // bar 1: xl ready

      // ================= LAYER 0 (m-split) =================
      #pragma unroll
      for (int mh = 0; mh < 2; mh++){
        f32x4 acc[8][2];
        #pragma unroll
        for (int i = 0; i < 8; i++){
          f32x4 bv = *(const f32x4*)(bias_g + (w*8 + i)*16 + nul*4);
          acc[i][0] = bv; acc[i][1] = bv;
        }
        for (int kb = 0; kb < 10; kb++){
          bf16x8 a0, a1;
          if (kb < 2){
            a0 = ld_xfrag(xl, mh*2+0, kb, l); a1 = ld_xfrag(xl, mh*2+1, kb, l);
          } else {
            a0 = ld_hfrag(h0l, mh*2+0, kb-2, l); a1 = ld_hfrag(h0l, mh*2+1, kb-2, l);
          }
          #pragma unroll
          for (int i = 0; i < 8; i++){
            const bf16x8 bf = *(const bf16x8*)(wbase + (((size_t)((w*8+i)*10 + kb))*64 + l)*8);
            acc[i][0] = __builtin_amdgcn_mfma_f32_16x16x32_bf16(bf, a0, acc[i][0], 0, 0, 0);
            acc[i][1] = __builtin_amdgcn_mfma_f32_16x16x32_bf16(bf, a1, acc[i][1], 0, 0, 0);
          }
        }
        __syncthreads();   // all waves done reading rows [32mh,32mh+32) (old h0 / x)

        // nonlinearity: gates live in acc regs (swap) — no LDS transpose
        #pragma unroll
        for (int i = 0; i < 8; i++){
          #pragma unroll
          for (int ml = 0; ml < 2; ml++){
            int m = mh*2 + ml;
            f32x4 g = acc[i][ml];
            float cn = sigm(g[1])*c0r[i][m] + sigm(g[0])*tanh_s(g[2]);
            float hn = sigm(g[3])*tanh_s(cn);
            c0r[i][m] = cn;
            int row  = m*16 + nrow;
            int unit = (w*8 + i)*4 + nul;
            st_h(h0l, row, unit, f2bf(hn));
            unsigned int pk = epl[row];
            if (pk >> 31){
              int len = (int)(pk & 255) + 1;
              int start = (pk >> 8) & 255;
              if (s == len - 1 && start + len == Tt){
                int b = (pk >> 16) & 127;
                size_t base = ((size_t)(b*Nn + n)*2 + 0)*Hh + unit;
                __builtin_nontemporal_store(hn, &out[OUT_HN + base]);
                __builtin_nontemporal_store(cn, &out[OUT_CN + base]);
              }
            }
          }
        }
      }
      __syncthreads();   // all h0_new rows visible for layer 1

      // ================= LAYER 1 (m-split) =================
      #pragma unroll
      for (int mh = 0; mh < 2; mh++){
        f32x4 acc[8][2];
        #pragma unroll
        for (int i = 0; i < 8; i++){
          f32x4 bv = *(const f32x4*)(bias_g + G4H + (w*8 + i)*16 + nul*4);
          acc[i][0] = bv; acc[i][1] = bv;
        }
        for (int kb = 0; kb < 16; kb++){
          bf16x8 a0, a1;
          if (kb < 8){
            a0 = ld_hfrag(h0l, mh*2+0, kb, l); a1 = ld_hfrag(h0l, mh*2+1, kb, l);
          } else {
            a0 = ld_hfrag(h1l, mh*2+0, kb-8, l); a1 = ld_hfrag(h1l, mh*2+1, kb-8, l);
          }
          #pragma unroll
          for (int i = 0; i < 8; i++){
            const bf16x8 bf = *(const bf16x8*)(wbase + (((size_t)(640 + (w*8+i)*16 + kb))*64 + l)*8);
            acc[i][0] = __builtin_amdgcn_mfma_f32_16x16x32_bf16(bf, a0, acc[i][0], 0, 0, 0);
            acc[i][1] = __builtin_amdgcn_mfma_f32_16x16x32_bf16(bf, a1, acc[i][1], 0, 0, 0);
          }
        }
        __syncthreads();   // all waves done reading rows [32mh,..) of h0new/h1old

        #pragma unroll
        for (int i = 0; i < 8; i++){
          #pragma unroll
          for (int ml = 0; ml < 2; ml++){
            int m = mh*2 + ml;
            f32x4 g = acc[i][ml];
            float cn = sigm(g[1])*c1r[i][m] + sigm(g[0])*tanh_s(g[2]);
            float hn = sigm(g[3])*tanh_s(cn);
            c1r[i][m] = cn;
            int row  = m*16 + nrow;
            int unit = (w*8 + i)*4 + nul;
            st_h(h1l, row, unit, f2bf(hn));
            unsigned int pk = epl[row];
            if (pk >> 31){
              int len = (int)(pk & 255) + 1;
              int start = (pk >> 8) & 255;
              if (s == len - 1 && start + len == Tt){
                int b = (pk >> 16) & 127;
                size_t base = ((size_t)(b*Nn + n)*2 + 1)*Hh + unit;
                __builtin_nontemporal_store(hn, &out[OUT_HN + base]);
                __builtin_nontemporal_store(cn, &out[OUT_CN + base]);
              }
            }
          }
        }
      }
      __syncthreads();   // h1_new visible for output read

      // ---- output write: output[b, t, n, :] = h1_new (256B segments, NT) ----
      #pragma unroll
      for (int r2 = 0; r2 < 2; r2++){
        int row = r2*32 + (tid >> 4);
        unsigned int pk = epl[row];
        int len = (pk >> 31) ? (int)(pk & 255) + 1 : 0;
        if (s < len){
          int b = (pk >> 16) & 127;
          int t = (int)((pk >> 8) & 255) + s;
          int l16 = tid & 15;
          int swz = (row & 7) << 4;
          float* op = out + (((size_t)b*Tt + t)*Nn + n)*Hh;
          #pragma unroll
          for (int k = 0; k < 4; k++){
            int off = (row*(Hh*2) + k*128 + l16*8) ^ swz;
            ushort4 u = *(const ushort4*)((const char*)h1l + off);
            f32x4 v = { bf2f((short)u.x), bf2f((short)u.y), bf2f((short)u.z), bf2f((short)u.w) };
            __builtin_nontemporal_store(v, (f32x4*)(op + k*64 + l16*4));
          }
        }
      }
      // no trailing barrier needed: next writers of h1l are >=2 barriers away
    } // s loop
  } // work loop
}

// ============== launch ==============
extern "C" void kernel_launch(void* const* d_in, const int* in_sizes, int n_in,
                              void* d_out, int out_size, void* d_ws, size_t ws_size,
                              hipStream_t stream)
{
  const float* x    = (const float*)d_in[0];
  const unsigned char* ii = (const unsigned char*)d_in[1];
  const float* Wih0 = (const float*)d_in[2];
  const float* Whh0 = (const float*)d_in[3];
  const float* bih0 = (const float*)d_in[4];
  const float* bhh0 = (const float*)d_in[5];
  const float* Wih1 = (const float*)d_in[6];
  const float* Whh1 = (const float*)d_in[7];
  const float* bih1 = (const float*)d_in[8];
  const float* bhh1 = (const float*)d_in[9];
  float* out = (float*)d_out;
  char* ws = (char*)d_ws;

  int* ctrl = (int*)(ws + WS_CTRL);
  int* hist = (int*)(ws + WS_HIST);
  unsigned int* sorted = (unsigned int*)(ws + WS_SORT);
  float* bpk = (float*)(ws + WS_BIAS);
  unsigned short* wpkp = (unsigned short*)(ws + WS_WPK);

  hipMemsetAsync(d_ws, 0, 8192, stream);
  k_prep1 <<<1, 128, 0, stream>>>(ii, ctrl, hist);
  k_prep2 <<<1, 128, 0, stream>>>(ii, ctrl, hist, sorted);
  k_packw <<<Nn*TILES_PER_AGENT, 64, 0, stream>>>(Wih0, Whh0, Wih1, Whh1,
                                                  bih0, bhh0, bih1, bhh1, wpkp, bpk);
  k_main  <<<512, 512, 0, stream>>>(x, wpkp, bpk, sorted, ctrl, out);
}

// Round 8
// 3236.199 us; speedup vs baseline: 1.3404x; 1.0942x over previous
//
#include <hip/hip_runtime.h>
#include <stdint.h>

// Problem constants
#define Bb   128
#define Tt   256
#define Nn   4
#define Dd   64
#define Hh   256
#define G4H  1024          // 4*H
#define MR   64            // episode lanes (rows) per work item

// d_out layout: output (B,T,N,H) | h_n (B,N,L,H) | c_n (B,N,L,H)
#define OUT_HN 33554432    // 128*256*4*256
#define OUT_CN 33816576    // OUT_HN + 128*4*2*256

// workspace byte offsets
#define WS_CTRL 0          // 64 ints: [0]=stride mode, [1]=E, [2]=nchunks, [4..7]=work ctrs
#define WS_HIST 1024       // 257 ints
#define WS_SORT 8192       // 32768 u32 packed episodes (sorted desc by len)
#define WS_BIAS 139264     // N*2*1024 f32 packed bias
#define WS_WPK  262144     // packed bf16 weights: 4 agents * 1664 tiles * 1KB
#define TILES_PER_AGENT 1664   // 64 ntiles * (10 kb L0 + 16 kb L1)

typedef __attribute__((ext_vector_type(4))) float f32x4;
typedef __attribute__((ext_vector_type(8))) short bf16x8;

__device__ __forceinline__ unsigned short f2bf(float f){
  union { float f; unsigned u; } v; v.f = f;
  unsigned r = v.u + 0x7FFFu + ((v.u >> 16) & 1u);  // RNE
  return (unsigned short)(r >> 16);
}
__device__ __forceinline__ float bf2f(short s){
  union { unsigned u; float f; } v; v.u = ((unsigned)(unsigned short)s) << 16;
  return v.f;
}
// fast sigmoid / tanh via v_exp + v_rcp (absmax margin: 0.004 vs 0.0231 threshold)
__device__ __forceinline__ float sigm(float x){
  return __builtin_amdgcn_rcpf(1.f + __expf(-x));
}
__device__ __forceinline__ float tanh_s(float x){
  return 1.f - 2.f * __builtin_amdgcn_rcpf(1.f + __expf(2.f * x));
}

// ---- LDS swizzle helpers (XOR bit4 with row&7 -> conflict-free b128 column reads) ----
__device__ __forceinline__ void st_h(unsigned short* hl, int row, int col, unsigned short v){
  int off = (row * (Hh*2) + col * 2) ^ ((row & 7) << 4);
  *(unsigned short*)((char*)hl + off) = v;
}
__device__ __forceinline__ bf16x8 ld_hfrag(const unsigned short* hl, int m, int kb, int l){
  int row = m*16 + (l & 15);
  int off = (row * (Hh*2) + kb*64 + ((l >> 4) << 4)) ^ ((row & 7) << 4);
  return *(const bf16x8*)((const char*)hl + off);
}
__device__ __forceinline__ bf16x8 ld_xfrag(const unsigned short* xl, int m, int kb, int l){
  int row = m*16 + (l & 15);
  int off = (row * (Dd*2) + kb*64 + ((l >> 4) << 4)) ^ ((row & 7) << 4);
  return *(const bf16x8*)((const char*)xl + off);
}

__device__ __forceinline__ bool get_flag(const unsigned char* p, int t, int stride){
  if (stride == 1) return p[t] != 0;
  return ((const int*)p)[t] != 0;   // covers int32 and f32 bit patterns
}

// ============== prep kernels (3 dispatches before k_main) ==============

// detect is_init storage (bool8 vs 4-byte) + per-row episode-length histogram
__global__ void k_prep1(const unsigned char* ii, int* ctrl, int* hist){
  __shared__ int s_cnt;
  __shared__ int s_stride;
  int tid = threadIdx.x;          // 128 threads, one per b
  if (tid == 0) s_cnt = 0;
  __syncthreads();
  atomicAdd(&s_cnt, (ii[2*tid] != 0) + (ii[2*tid+1] != 0));
  __syncthreads();
  if (tid == 0){ s_stride = (s_cnt > 80) ? 1 : 4; ctrl[0] = s_stride; }
  __syncthreads();
  int stride = s_stride;
  const unsigned char* p = ii + (size_t)tid * Tt * stride;
  int start = 0;
  for (int t = 1; t < Tt; t++){
    if (get_flag(p, t, stride)){ atomicAdd(&hist[t - start], 1); start = t; }
  }
  atomicAdd(&hist[Tt - start], 1);
}

// serial scan (thread 0, offs in LDS) + scatter episodes sorted desc by length
__global__ void k_prep2(const unsigned char* ii, int* ctrl, const int* hist,
                        unsigned int* sorted){
  __shared__ int offs_s[Tt + 1];
  int tid = threadIdx.x;          // 128 threads
  if (tid == 0){
    int run = 0;
    for (int len = Tt; len >= 1; len--){ offs_s[len] = run; run += hist[len]; }
    ctrl[1] = run;                     // E
    ctrl[2] = (run + MR - 1) / MR;     // nchunks
  }
  __syncthreads();
  int stride = ctrl[0];
  const unsigned char* p = ii + (size_t)tid * Tt * stride;
  int start = 0;
  for (int t = 1; t < Tt; t++){
    if (get_flag(p, t, stride)){
      int len = t - start;
      int pos = atomicAdd(&offs_s[len], 1);
      sorted[pos] = 0x80000000u | ((unsigned)tid << 16) | ((unsigned)start << 8) | (unsigned)(len - 1);
      start = t;
    }
  }
  int len = Tt - start;
  int pos = atomicAdd(&offs_s[len], 1);
  sorted[pos] = 0x80000000u | ((unsigned)tid << 16) | ((unsigned)start << 8) | (unsigned)(len - 1);
}

// Pack weights to bf16 in exact MFMA fragment order (+ bias pack folded into blocks 0..127).
__global__ void k_packw(const float* __restrict__ Wih0, const float* __restrict__ Whh0,
                        const float* __restrict__ Wih1, const float* __restrict__ Whh1,
                        const float* __restrict__ bih0, const float* __restrict__ bhh0,
                        const float* __restrict__ bih1, const float* __restrict__ bhh1,
                        unsigned short* __restrict__ wpk, float* __restrict__ bpk){
  int bid = blockIdx.x;            // 0..6655
  int l = threadIdx.x;             // 0..63
  int n = bid / TILES_PER_AGENT;
  int r = bid % TILES_PER_AGENT;
  int layer, ntile, kb;
  if (r < 640){ layer = 0; ntile = r / 10; kb = r % 10; }
  else        { layer = 1; r -= 640; ntile = r / 16; kb = r % 16; }
  int col_sub = l >> 2;
  int k8      = (l & 3) * 8;
  int col  = ntile*16 + col_sub;
  int grow = (col & 3)*Hh + (col >> 2);
  const float* src;
  if (layer == 0){
    if (kb < 2) src = Wih0 + ((size_t)(n*G4H + grow))*Dd + kb*32 + k8;        // x part
    else        src = Whh0 + ((size_t)(n*G4H + grow))*Hh + (kb-2)*32 + k8;    // h0 part
  } else {
    if (kb < 8) src = Wih1 + ((size_t)(n*G4H + grow))*Hh + kb*32 + k8;        // h0_new part
    else        src = Whh1 + ((size_t)(n*G4H + grow))*Hh + (kb-8)*32 + k8;    // h1 part
  }
  int tl = (layer == 0) ? (ntile*10 + kb) : (640 + ntile*16 + kb);
  int lp = ((l & 3) << 4) | (l >> 2);
  unsigned short* dst = wpk + (((size_t)n*TILES_PER_AGENT + tl)*64 + lp)*8;
  #pragma unroll
  for (int j = 0; j < 8; j++) dst[j] = f2bf(src[j]);

  // folded bias pack: ids 0..8191 handled by blocks 0..127
  int id = bid*64 + l;
  if (id < Nn*2*G4H){
    int nb = id >> 11; int rb = id & 2047; int lyr = rb >> 10; int c = rb & 1023;
    int gr = (c & 3)*Hh + (c >> 2);
    float v = (lyr == 0) ? (bih0[nb*G4H + gr] + bhh0[nb*G4H + gr])
                         : (bih1[nb*G4H + gr] + bhh1[nb*G4H + gr]);
    bpk[id] = v;
  }
}

// ============== main kernel ==============
// 512 blocks x 512 threads, 2 blocks/CU (LDS 78KB, VGPR cap 128 via (512,2)).
// SPILL FIX vs R7: bias is staged in LDS (bf16) and read per-acc-init. R7 read
// bias from GLOBAL; those 16 loop-invariant f32x4 loads got hoisted = 64 live
// VGPRs -> acc/c-state spilled to scratch (FETCH 4.4GB/WRITE 2.4GB phantom).
// LDS reads can't be hoisted across __syncthreads -> pressure stays ~R5 level,
// which fit the 128-reg cap with zero spill.
// Operand swap kept: mfma(W_frag, x_frag) -> gates i,f,g,o of (episode=l&15,
// unit=l>>4) land in acc regs 0..3 directly; no LDS transpose.
__launch_bounds__(512, 2)
__global__ void k_main(const float* __restrict__ x_in,
                       const unsigned short* __restrict__ wpk,
                       const float* __restrict__ bpk,
                       const unsigned int* __restrict__ sorted,
                       int* __restrict__ ctrl,
                       float* __restrict__ out)
{
  __shared__ unsigned short h0l[MR*Hh];     // 32KB, swizzled bf16
  __shared__ unsigned short h1l[MR*Hh];     // 32KB
  __shared__ unsigned short xl [MR*Dd];     // 8KB
  __shared__ unsigned short biasl[2*G4H];   // 4KB bf16 packed bias (this agent)
  __shared__ unsigned int epl[MR];
  __shared__ int item_s;

  const int tid = threadIdx.x;
  const int w   = tid >> 6;
  const int l   = tid & 63;
  const int n   = blockIdx.x & 3;           // deterministic agent assignment
  const int E       = ctrl[1];
  const int nchunks = ctrl[2];

  const unsigned short* wbase = wpk + (size_t)n * TILES_PER_AGENT * 64 * 8;

  for (int i = tid; i < 2*G4H; i += 512) biasl[i] = f2bf(bpk[n*2*G4H + i]);

  const int nrow = l & 15;   // lane's episode row within M-tile
  const int nul  = l >> 4;   // lane's unit_local 0..3

  while (true){
    __syncthreads();
    if (tid == 0) item_s = atomicAdd(&ctrl[4 + n], 1);
    __syncthreads();
    int chunk = item_s;
    if (chunk >= nchunks) break;

    if (tid < MR){
      int idx = chunk*MR + tid;
      epl[tid] = (idx < E) ? sorted[idx] : 0u;
    }
    for (int i = tid; i < MR*Hh/4; i += 512){
      ((ushort4*)h0l)[i] = make_ushort4(0,0,0,0);
      ((ushort4*)h1l)[i] = make_ushort4(0,0,0,0);
    }
    __syncthreads();

    unsigned int ep0 = epl[0];
    int maxlen = (ep0 >> 31) ? (int)(ep0 & 255) + 1 : 0;  // sorted desc -> lane0 is max

    float c0r[8][4], c1r[8][4];
    #pragma unroll
    for (int i = 0; i < 8; i++)
      #pragma unroll
      for (int m = 0; m < 4; m++){ c0r[i][m]=0.f; c1r[i][m]=0.f; }

    #pragma unroll 1
    for (int s = 0; s < maxlen; s++){
      // ---- stage x_t (fp32 -> bf16, swizzled; zeros for finished lanes) ----
      #pragma unroll
      for (int r2 = 0; r2 < 2; r2++){
        int row = r2*32 + (tid >> 4);
        int d4  = (tid & 15) * 4;
        unsigned int pk = epl[row];
        int len = (pk >> 31) ? (int)(pk & 255) + 1 : 0;
        ushort4 u = make_ushort4(0,0,0,0);
        if (s < len){
          int b = (pk >> 16) & 127;
          int t = (int)((pk >> 8) & 255) + s;
          const float* xp = x_in + (((size_t)b*Tt + t)*Nn + n)*Dd + d4;
          f32x4 v = *(const f32x4*)xp;
          u.x = f2bf(v[0]); u.y = f2bf(v[1]); u.z = f2bf(v[2]); u.w = f2bf(v[3]);
        }
        int off = (row*(Dd*2) + d4*2) ^ ((row & 7) << 4);
        *(ushort4*)((char*)xl + off) = u;
      }
      __syncthreads();                                   // bar 1: xl ready

      // ================= LAYER 0 (m-split) =================
      #pragma unroll
      for (int mh = 0; mh < 2; mh++){
        f32x4 acc[8][2];
        #pragma unroll
        for (int i = 0; i < 8; i++){
          ushort4 bu = *(const ushort4*)&biasl[(w*8 + i)*16 + nul*4];
          f32x4 bv = { bf2f((short)bu.x), bf2f((short)bu.y),
                       bf2f((short)bu.z), bf2f((short)bu.w) };
          acc[i][0] = bv; acc[i][1] = bv;
        }
        for (int kb = 0; kb < 10; kb++){
          bf16x8 a0, a1;
          if (kb < 2){
            a0 = ld_xfrag(xl, mh*2+0, kb, l); a1 = ld_xfrag(xl, mh*2+1, kb, l);
          } else {
            a0 = ld_hfrag(h0l, mh*2+0, kb-2, l); a1 = ld_hfrag(h0l, mh*2+1, kb-2, l);
          }
          #pragma unroll
          for (int i = 0; i < 8; i++){
            const bf16x8 bf = *(const bf16x8*)(wbase + (((size_t)((w*8+i)*10 + kb))*64 + l)*8);
            acc[i][0] = __builtin_amdgcn_mfma_f32_16x16x32_bf16(bf, a0, acc[i][0], 0, 0, 0);
            acc[i][1] = __builtin_amdgcn_mfma_f32_16x16x32_bf16(bf, a1, acc[i][1], 0, 0, 0);
          }
        }
        __syncthreads();   // all waves done reading rows [32mh,32mh+32) (old h0 / x)

        // nonlinearity: gates live in acc regs (swap) — no LDS transpose
        #pragma unroll
        for (int i = 0; i < 8; i++){
          #pragma unroll
          for (int ml = 0; ml < 2; ml++){
            int m = mh*2 + ml;
            f32x4 g = acc[i][ml];
            float cn = sigm(g[1])*c0r[i][m] + sigm(g[0])*tanh_s(g[2]);
            float hn = sigm(g[3])*tanh_s(cn);
            c0r[i][m] = cn;
            int row  = m*16 + nrow;
            int unit = (w*8 + i)*4 + nul;
            st_h(h0l, row, unit, f2bf(hn));
            unsigned int pk = epl[row];
            if (pk >> 31){
              int len = (int)(pk & 255) + 1;
              int start = (pk >> 8) & 255;
              if (s == len - 1 && start + len == Tt){
                int b = (pk >> 16) & 127;
                size_t base = ((size_t)(b*Nn + n)*2 + 0)*Hh + unit;
                __builtin_nontemporal_store(hn, &out[OUT_HN + base]);
                __builtin_nontemporal_store(cn, &out[OUT_CN + base]);
              }
            }
          }
        }
      }
      __syncthreads();   // all h0_new rows visible for layer 1

      // ================= LAYER 1 (m-split) =================
      #pragma unroll
      for (int mh = 0; mh < 2; mh++){
        f32x4 acc[8][2];
        #pragma unroll
        for (int i = 0; i < 8; i++){
          ushort4 bu = *(const ushort4*)&biasl[G4H + (w*8 + i)*16 + nul*4];
          f32x4 bv = { bf2f((short)bu.x), bf2f((short)bu.y),
                       bf2f((short)bu.z), bf2f((short)bu.w) };
          acc[i][0] = bv; acc[i][1] = bv;
        }
        for (int kb = 0; kb < 16; kb++){
          bf16x8 a0, a1;
          if (kb < 8){
            a0 = ld_hfrag(h0l, mh*2+0, kb, l); a1 = ld_hfrag(h0l, mh*2+1, kb, l);
          } else {
            a0 = ld_hfrag(h1l, mh*2+0, kb-8, l); a1 = ld_hfrag(h1l, mh*2+1, kb-8, l);
          }
          #pragma unroll
          for (int i = 0; i < 8; i++){
            const bf16x8 bf = *(const bf16x8*)(wbase + (((size_t)(640 + (w*8+i)*16 + kb))*64 + l)*8);
            acc[i][0] = __builtin_amdgcn_mfma_f32_16x16x32_bf16(bf, a0, acc[i][0], 0, 0, 0);
            acc[i][1] = __builtin_amdgcn_mfma_f32_16x16x32_bf16(bf, a1, acc[i][1], 0, 0, 0);
          }
        }
        __syncthreads();   // all waves done reading rows [32mh,..) of h0new/h1old

        #pragma unroll
        for (int i = 0; i < 8; i++){
          #pragma unroll
          for (int ml = 0; ml < 2; ml++){
            int m = mh*2 + ml;
            f32x4 g = acc[i][ml];
            float cn = sigm(g[1])*c1r[i][m] + sigm(g[0])*tanh_s(g[2]);
            float hn = sigm(g[3])*tanh_s(cn);
            c1r[i][m] = cn;
            int row  = m*16 + nrow;
            int unit = (w*8 + i)*4 + nul;
            st_h(h1l, row, unit, f2bf(hn));
            unsigned int pk = epl[row];
            if (pk >> 31){
              int len = (int)(pk & 255) + 1;
              int start = (pk >> 8) & 255;
              if (s == len - 1 && start + len == Tt){
                int b = (pk >> 16) & 127;
                size_t base = ((size_t)(b*Nn + n)*2 + 1)*Hh + unit;
                __builtin_nontemporal_store(hn, &out[OUT_HN + base]);
                __builtin_nontemporal_store(cn, &out[OUT_CN + base]);
              }
            }
          }
        }
      }
      __syncthreads();   // h1_new visible for output read

      // ---- output write: output[b, t, n, :] = h1_new (256B segments, NT) ----
      #pragma unroll
      for (int r2 = 0; r2 < 2; r2++){
        int row = r2*32 + (tid >> 4);
        unsigned int pk = epl[row];
        int len = (pk >> 31) ? (int)(pk & 255) + 1 : 0;
        if (s < len){
          int b = (pk >> 16) & 127;
          int t = (int)((pk >> 8) & 255) + s;
          int l16 = tid & 15;
          int swz = (row & 7) << 4;
          float* op = out + (((size_t)b*Tt + t)*Nn + n)*Hh;
          #pragma unroll
          for (int k = 0; k < 4; k++){
            int off = (row*(Hh*2) + k*128 + l16*8) ^ swz;
            ushort4 u = *(const ushort4*)((const char*)h1l + off);
            f32x4 v = { bf2f((short)u.x), bf2f((short)u.y), bf2f((short)u.z), bf2f((short)u.w) };
            __builtin_nontemporal_store(v, (f32x4*)(op + k*64 + l16*4));
          }
        }
      }
      // no trailing barrier needed: next writers of h1l are >=2 barriers away
    } // s loop
  } // work loop
}

// ============== launch ==============
extern "C" void kernel_launch(void* const* d_in, const int* in_sizes, int n_in,
                              void* d_out, int out_size, void* d_ws, size_t ws_size,
                              hipStream_t stream)
{
  const float* x    = (const float*)d_in[0];
  const unsigned char* ii = (const unsigned char*)d_in[1];
  const float* Wih0 = (const float*)d_in[2];
  const float* Whh0 = (const float*)d_in[3];
  const float* bih0 = (const float*)d_in[4];
  const float* bhh0 = (const float*)d_in[5];
  const float* Wih1 = (const float*)d_in[6];
  const float* Whh1 = (const float*)d_in[7];
  const float* bih1 = (const float*)d_in[8];
  const float* bhh1 = (const float*)d_in[9];
  float* out = (float*)d_out;
  char* ws = (char*)d_ws;

  int* ctrl = (int*)(ws + WS_CTRL);
  int* hist = (int*)(ws + WS_HIST);
  unsigned int* sorted = (unsigned int*)(ws + WS_SORT);
  float* bpk = (float*)(ws + WS_BIAS);
  unsigned short* wpkp = (unsigned short*)(ws + WS_WPK);

  hipMemsetAsync(d_ws, 0, 8192, stream);
  k_prep1 <<<1, 128, 0, stream>>>(ii, ctrl, hist);
  k_prep2 <<<1, 128, 0, stream>>>(ii, ctrl, hist, sorted);
  k_packw <<<Nn*TILES_PER_AGENT, 64, 0, stream>>>(Wih0, Whh0, Wih1, Whh1,
                                                  bih0, bhh0, bih1, bhh1, wpkp, bpk);
  k_main  <<<512, 512, 0, stream>>>(x, wpkp, bpk, sorted, ctrl, out);
}

// Round 9
// 1130.185 us; speedup vs baseline: 3.8381x; 2.8634x over previous
//
#include <hip/hip_runtime.h>
#include <stdint.h>

// Problem constants
#define Bb   128
#define Tt   256
#define Nn   4
#define Dd   64
#define Hh   256
#define G4H  1024          // 4*H
#define MR   64            // episode lanes (rows) per work item

// d_out layout: output (B,T,N,H) | h_n (B,N,L,H) | c_n (B,N,L,H)
#define OUT_HN 33554432    // 128*256*4*256
#define OUT_CN 33816576    // OUT_HN + 128*4*2*256

// workspace byte offsets
#define WS_CTRL 0          // 64 ints: [0]=stride mode, [1]=E, [2]=nchunks, [4..7]=work ctrs
#define WS_HIST 1024       // 257 ints
#define WS_SORT 8192       // 32768 u32 packed episodes (sorted desc by len)
#define WS_BIAS 139264     // N*2*1024 f32 packed bias
#define WS_WPK  262144     // packed bf16 weights: 4 agents * 1664 tiles * 1KB
#define TILES_PER_AGENT 1664   // 64 ntiles * (10 kb L0 + 16 kb L1)

typedef __attribute__((ext_vector_type(4))) float f32x4;
typedef __attribute__((ext_vector_type(8))) short bf16x8;

__device__ __forceinline__ unsigned short f2bf(float f){
  union { float f; unsigned u; } v; v.f = f;
  unsigned r = v.u + 0x7FFFu + ((v.u >> 16) & 1u);  // RNE
  return (unsigned short)(r >> 16);
}
__device__ __forceinline__ float bf2f(short s){
  union { unsigned u; float f; } v; v.u = ((unsigned)(unsigned short)s) << 16;
  return v.f;
}
// fast sigmoid / tanh via v_exp + v_rcp (absmax margin: 0.004 vs 0.0231 threshold)
__device__ __forceinline__ float sigm(float x){
  return __builtin_amdgcn_rcpf(1.f + __expf(-x));
}
__device__ __forceinline__ float tanh_s(float x){
  return 1.f - 2.f * __builtin_amdgcn_rcpf(1.f + __expf(2.f * x));
}

// ---- LDS swizzle helpers (XOR bit4 with row&7 -> conflict-free b128 column reads) ----
__device__ __forceinline__ void st_h(unsigned short* hl, int row, int col, unsigned short v){
  int off = (row * (Hh*2) + col * 2) ^ ((row & 7) << 4);
  *(unsigned short*)((char*)hl + off) = v;
}
__device__ __forceinline__ bf16x8 ld_hfrag(const unsigned short* hl, int m, int kb, int l){
  int row = m*16 + (l & 15);
  int off = (row * (Hh*2) + kb*64 + ((l >> 4) << 4)) ^ ((row & 7) << 4);
  return *(const bf16x8*)((const char*)hl + off);
}
__device__ __forceinline__ bf16x8 ld_xfrag(const unsigned short* xl, int m, int kb, int l){
  int row = m*16 + (l & 15);
  int off = (row * (Dd*2) + kb*64 + ((l >> 4) << 4)) ^ ((row & 7) << 4);
  return *(const bf16x8*)((const char*)xl + off);
}

__device__ __forceinline__ bool get_flag(const unsigned char* p, int t, int stride){
  if (stride == 1) return p[t] != 0;
  return ((const int*)p)[t] != 0;   // covers int32 and f32 bit patterns
}

// ============== prep kernels (3 dispatches before k_main) ==============

// detect is_init storage (bool8 vs 4-byte) + per-row episode-length histogram
__global__ void k_prep1(const unsigned char* ii, int* ctrl, int* hist){
  __shared__ int s_cnt;
  __shared__ int s_stride;
  int tid = threadIdx.x;          // 128 threads, one per b
  if (tid == 0) s_cnt = 0;
  __syncthreads();
  atomicAdd(&s_cnt, (ii[2*tid] != 0) + (ii[2*tid+1] != 0));
  __syncthreads();
  if (tid == 0){ s_stride = (s_cnt > 80) ? 1 : 4; ctrl[0] = s_stride; }
  __syncthreads();
  int stride = s_stride;
  const unsigned char* p = ii + (size_t)tid * Tt * stride;
  int start = 0;
  for (int t = 1; t < Tt; t++){
    if (get_flag(p, t, stride)){ atomicAdd(&hist[t - start], 1); start = t; }
  }
  atomicAdd(&hist[Tt - start], 1);
}

// serial scan (thread 0, offs in LDS) + scatter episodes sorted desc by length
__global__ void k_prep2(const unsigned char* ii, int* ctrl, const int* hist,
                        unsigned int* sorted){
  __shared__ int offs_s[Tt + 1];
  int tid = threadIdx.x;          // 128 threads
  if (tid == 0){
    int run = 0;
    for (int len = Tt; len >= 1; len--){ offs_s[len] = run; run += hist[len]; }
    ctrl[1] = run;                     // E
    ctrl[2] = (run + MR - 1) / MR;     // nchunks
  }
  __syncthreads();
  int stride = ctrl[0];
  const unsigned char* p = ii + (size_t)tid * Tt * stride;
  int start = 0;
  for (int t = 1; t < Tt; t++){
    if (get_flag(p, t, stride)){
      int len = t - start;
      int pos = atomicAdd(&offs_s[len], 1);
      sorted[pos] = 0x80000000u | ((unsigned)tid << 16) | ((unsigned)start << 8) | (unsigned)(len - 1);
      start = t;
    }
  }
  int len = Tt - start;
  int pos = atomicAdd(&offs_s[len], 1);
  sorted[pos] = 0x80000000u | ((unsigned)tid << 16) | ((unsigned)start << 8) | (unsigned)(len - 1);
}

// Pack weights to bf16 in exact MFMA fragment order (+ bias pack folded into blocks 0..127).
__global__ void k_packw(const float* __restrict__ Wih0, const float* __restrict__ Whh0,
                        const float* __restrict__ Wih1, const float* __restrict__ Whh1,
                        const float* __restrict__ bih0, const float* __restrict__ bhh0,
                        const float* __restrict__ bih1, const float* __restrict__ bhh1,
                        unsigned short* __restrict__ wpk, float* __restrict__ bpk){
  int bid = blockIdx.x;            // 0..6655
  int l = threadIdx.x;             // 0..63
  int n = bid / TILES_PER_AGENT;
  int r = bid % TILES_PER_AGENT;
  int layer, ntile, kb;
  if (r < 640){ layer = 0; ntile = r / 10; kb = r % 10; }
  else        { layer = 1; r -= 640; ntile = r / 16; kb = r % 16; }
  int col_sub = l >> 2;
  int k8      = (l & 3) * 8;
  int col  = ntile*16 + col_sub;
  int grow = (col & 3)*Hh + (col >> 2);
  const float* src;
  if (layer == 0){
    if (kb < 2) src = Wih0 + ((size_t)(n*G4H + grow))*Dd + kb*32 + k8;        // x part
    else        src = Whh0 + ((size_t)(n*G4H + grow))*Hh + (kb-2)*32 + k8;    // h0 part
  } else {
    if (kb < 8) src = Wih1 + ((size_t)(n*G4H + grow))*Hh + kb*32 + k8;        // h0_new part
    else        src = Whh1 + ((size_t)(n*G4H + grow))*Hh + (kb-8)*32 + k8;    // h1 part
  }
  int tl = (layer == 0) ? (ntile*10 + kb) : (640 + ntile*16 + kb);
  int lp = ((l & 3) << 4) | (l >> 2);
  unsigned short* dst = wpk + (((size_t)n*TILES_PER_AGENT + tl)*64 + lp)*8;
  #pragma unroll
  for (int j = 0; j < 8; j++) dst[j] = f2bf(src[j]);

  // folded bias pack: ids 0..8191 handled by blocks 0..127
  int id = bid*64 + l;
  if (id < Nn*2*G4H){
    int nb = id >> 11; int rb = id & 2047; int lyr = rb >> 10; int c = rb & 1023;
    int gr = (c & 3)*Hh + (c >> 2);
    float v = (lyr == 0) ? (bih0[nb*G4H + gr] + bhh0[nb*G4H + gr])
                         : (bih1[nb*G4H + gr] + bhh1[nb*G4H + gr]);
    bpk[id] = v;
  }
}

// ============== main kernel ==============
// 256 blocks x 512 threads, 1 block/CU. REGISTER ARITHMETIC (R3/R6/R7/R8
// post-mortem): unified VGPR+AGPR file = 512 regs/SIMD-slot; an 8-wave block
// needs 2 waves/SIMD -> hard cap 256 regs/wave. This kernel's state is
// acc(128) + c(64) + frags/addr (~50) ~= 240 <= 256, so (512,1) fits with NO
// spill; any 2-blocks/CU config caps at 128 and MUST spill (R3/R6/R7/R8 all
// showed GB-scale phantom FETCH/WRITE). NO m-split anymore: acc[8][4] -> the
// per-CU weight stream halves to 1.66 MB/step (the real R5 bottleneck), and
// barriers drop 7 -> 5 per step.
__launch_bounds__(512, 1)
__global__ void k_main(const float* __restrict__ x_in,
                       const unsigned short* __restrict__ wpk,
                       const float* __restrict__ bpk,
                       const unsigned int* __restrict__ sorted,
                       int* __restrict__ ctrl,
                       float* __restrict__ out)
{
  __shared__ unsigned short h0l[MR*Hh];     // 32KB, swizzled bf16
  __shared__ unsigned short h1l[MR*Hh];     // 32KB
  __shared__ unsigned short xl [MR*Dd];     // 8KB
  __shared__ unsigned short biasl[2*G4H];   // 4KB bf16 packed bias (this agent)
  __shared__ unsigned int epl[MR];
  __shared__ int item_s;

  const int tid = threadIdx.x;
  const int w   = tid >> 6;
  const int l   = tid & 63;
  const int n   = blockIdx.x & 3;           // deterministic agent assignment
  const int E       = ctrl[1];
  const int nchunks = ctrl[2];

  const unsigned short* wbase = wpk + (size_t)n * TILES_PER_AGENT * 64 * 8;

  for (int i = tid; i < 2*G4H; i += 512) biasl[i] = f2bf(bpk[n*2*G4H + i]);

  const int nrow = l & 15;   // lane's episode row within M-tile
  const int nul  = l >> 4;   // lane's unit_local 0..3

  while (true){
    __syncthreads();
    if (tid == 0) item_s = atomicAdd(&ctrl[4 + n], 1);
    __syncthreads();
    int chunk = item_s;
    if (chunk >= nchunks) break;

    if (tid < MR){
      int idx = chunk*MR + tid;
      epl[tid] = (idx < E) ? sorted[idx] : 0u;
    }
    for (int i = tid; i < MR*Hh/4; i += 512){
      ((ushort4*)h0l)[i] = make_ushort4(0,0,0,0);
      ((ushort4*)h1l)[i] = make_ushort4(0,0,0,0);
    }
    __syncthreads();

    unsigned int ep0 = epl[0];
    int maxlen = (ep0 >> 31) ? (int)(ep0 & 255) + 1 : 0;  // sorted desc -> lane0 is max

    float c0r[8][4], c1r[8][4];
    #pragma unroll
    for (int i = 0; i < 8; i++)
      #pragma unroll
      for (int m = 0; m < 4; m++){ c0r[i][m]=0.f; c1r[i][m]=0.f; }

    #pragma unroll 1
    for (int s = 0; s < maxlen; s++){
      // ---- stage x_t (fp32 -> bf16, swizzled; zeros for finished lanes) ----
      #pragma unroll
      for (int r2 = 0; r2 < 2; r2++){
        int row = r2*32 + (tid >> 4);
        int d4  = (tid & 15) * 4;
        unsigned int pk = epl[row];
        int len = (pk >> 31) ? (int)(pk & 255) + 1 : 0;
        ushort4 u = make_ushort4(0,0,0,0);
        if (s < len){
          int b = (pk >> 16) & 127;
          int t = (int)((pk >> 8) & 255) + s;
          const float* xp = x_in + (((size_t)b*Tt + t)*Nn + n)*Dd + d4;
          f32x4 v = *(const f32x4*)xp;
          u.x = f2bf(v[0]); u.y = f2bf(v[1]); u.z = f2bf(v[2]); u.w = f2bf(v[3]);
        }
        int off = (row*(Dd*2) + d4*2) ^ ((row & 7) << 4);
        *(ushort4*)((char*)xl + off) = u;
      }
      __syncthreads();                                   // bar 1: xl ready

      // ================= LAYER 0 (full M, acc[8][4]) =================
      {
        f32x4 acc[8][4];
        #pragma unroll
        for (int i = 0; i < 8; i++){
          ushort4 bu = *(const ushort4*)&biasl[(w*8 + i)*16 + nul*4];
          f32x4 bv = { bf2f((short)bu.x), bf2f((short)bu.y),
                       bf2f((short)bu.z), bf2f((short)bu.w) };
          #pragma unroll
          for (int m = 0; m < 4; m++) acc[i][m] = bv;
        }
        #pragma unroll 1
        for (int kb = 0; kb < 10; kb++){
          bf16x8 a0, a1, a2, a3;
          if (kb < 2){
            a0 = ld_xfrag(xl, 0, kb, l); a1 = ld_xfrag(xl, 1, kb, l);
            a2 = ld_xfrag(xl, 2, kb, l); a3 = ld_xfrag(xl, 3, kb, l);
          } else {
            a0 = ld_hfrag(h0l, 0, kb-2, l); a1 = ld_hfrag(h0l, 1, kb-2, l);
            a2 = ld_hfrag(h0l, 2, kb-2, l); a3 = ld_hfrag(h0l, 3, kb-2, l);
          }
          #pragma unroll
          for (int i = 0; i < 8; i++){
            const bf16x8 bf = *(const bf16x8*)(wbase + (((size_t)((w*8+i)*10 + kb))*64 + l)*8);
            acc[i][0] = __builtin_amdgcn_mfma_f32_16x16x32_bf16(bf, a0, acc[i][0], 0, 0, 0);
            acc[i][1] = __builtin_amdgcn_mfma_f32_16x16x32_bf16(bf, a1, acc[i][1], 0, 0, 0);
            acc[i][2] = __builtin_amdgcn_mfma_f32_16x16x32_bf16(bf, a2, acc[i][2], 0, 0, 0);
            acc[i][3] = __builtin_amdgcn_mfma_f32_16x16x32_bf16(bf, a3, acc[i][3], 0, 0, 0);
          }
        }
        __syncthreads();   // bar 2: all waves done reading h0l(old)/xl

        // nonlinearity: gates live in acc regs (swap) — no LDS transpose
        #pragma unroll
        for (int i = 0; i < 8; i++){
          #pragma unroll
          for (int m = 0; m < 4; m++){
            f32x4 g = acc[i][m];
            float cn = sigm(g[1])*c0r[i][m] + sigm(g[0])*tanh_s(g[2]);
            float hn = sigm(g[3])*tanh_s(cn);
            c0r[i][m] = cn;
            int row  = m*16 + nrow;
            int unit = (w*8 + i)*4 + nul;
            st_h(h0l, row, unit, f2bf(hn));
            unsigned int pk = epl[row];
            if (pk >> 31){
              int len = (int)(pk & 255) + 1;
              int start = (pk >> 8) & 255;
              if (s == len - 1 && start + len == Tt){
                int b = (pk >> 16) & 127;
                size_t base = ((size_t)(b*Nn + n)*2 + 0)*Hh + unit;
                __builtin_nontemporal_store(hn, &out[OUT_HN + base]);
                __builtin_nontemporal_store(cn, &out[OUT_CN + base]);
              }
            }
          }
        }
      }
      __syncthreads();   // bar 3: h0_new visible for layer 1

      // ================= LAYER 1 (full M, acc[8][4]) =================
      {
        f32x4 acc[8][4];
        #pragma unroll
        for (int i = 0; i < 8; i++){
          ushort4 bu = *(const ushort4*)&biasl[G4H + (w*8 + i)*16 + nul*4];
          f32x4 bv = { bf2f((short)bu.x), bf2f((short)bu.y),
                       bf2f((short)bu.z), bf2f((short)bu.w) };
          #pragma unroll
          for (int m = 0; m < 4; m++) acc[i][m] = bv;
        }
        #pragma unroll 1
        for (int kb = 0; kb < 16; kb++){
          bf16x8 a0, a1, a2, a3;
          if (kb < 8){
            a0 = ld_hfrag(h0l, 0, kb, l); a1 = ld_hfrag(h0l, 1, kb, l);
            a2 = ld_hfrag(h0l, 2, kb, l); a3 = ld_hfrag(h0l, 3, kb, l);
          } else {
            a0 = ld_hfrag(h1l, 0, kb-8, l); a1 = ld_hfrag(h1l, 1, kb-8, l);
            a2 = ld_hfrag(h1l, 2, kb-8, l); a3 = ld_hfrag(h1l, 3, kb-8, l);
          }
          #pragma unroll
          for (int i = 0; i < 8; i++){
            const bf16x8 bf = *(const bf16x8*)(wbase + (((size_t)(640 + (w*8+i)*16 + kb))*64 + l)*8);
            acc[i][0] = __builtin_amdgcn_mfma_f32_16x16x32_bf16(bf, a0, acc[i][0], 0, 0, 0);
            acc[i][1] = __builtin_amdgcn_mfma_f32_16x16x32_bf16(bf, a1, acc[i][1], 0, 0, 0);
            acc[i][2] = __builtin_amdgcn_mfma_f32_16x16x32_bf16(bf, a2, acc[i][2], 0, 0, 0);
            acc[i][3] = __builtin_amdgcn_mfma_f32_16x16x32_bf16(bf, a3, acc[i][3], 0, 0, 0);
          }
        }
        __syncthreads();   // bar 4: all waves done reading h0_new/h1l(old)

        #pragma unroll
        for (int i = 0; i < 8; i++){
          #pragma unroll
          for (int m = 0; m < 4; m++){
            f32x4 g = acc[i][m];
            float cn = sigm(g[1])*c1r[i][m] + sigm(g[0])*tanh_s(g[2]);
            float hn = sigm(g[3])*tanh_s(cn);
            c1r[i][m] = cn;
            int row  = m*16 + nrow;
            int unit = (w*8 + i)*4 + nul;
            st_h(h1l, row, unit, f2bf(hn));
            unsigned int pk = epl[row];
            if (pk >> 31){
              int len = (int)(pk & 255) + 1;
              int start = (pk >> 8) & 255;
              if (s == len - 1 && start + len == Tt){
                int b = (pk >> 16) & 127;
                size_t base = ((size_t)(b*Nn + n)*2 + 1)*Hh + unit;
                __builtin_nontemporal_store(hn, &out[OUT_HN + base]);
                __builtin_nontemporal_store(cn, &out[OUT_CN + base]);
              }
            }
          }
        }
      }
      __syncthreads();   // bar 5: h1_new visible for output read

      // ---- output write: output[b, t, n, :] = h1_new (256B segments, NT) ----
      #pragma unroll
      for (int r2 = 0; r2 < 2; r2++){
        int row = r2*32 + (tid >> 4);
        unsigned int pk = epl[row];
        int len = (pk >> 31) ? (int)(pk & 255) + 1 : 0;
        if (s < len){
          int b = (pk >> 16) & 127;
          int t = (int)((pk >> 8) & 255) + s;
          int l16 = tid & 15;
          int swz = (row & 7) << 4;
          float* op = out + (((size_t)b*Tt + t)*Nn + n)*Hh;
          #pragma unroll
          for (int k = 0; k < 4; k++){
            int off = (row*(Hh*2) + k*128 + l16*8) ^ swz;
            ushort4 u = *(const ushort4*)((const char*)h1l + off);
            f32x4 v = { bf2f((short)u.x), bf2f((short)u.y), bf2f((short)u.z), bf2f((short)u.w) };
            __builtin_nontemporal_store(v, (f32x4*)(op + k*64 + l16*4));
          }
        }
      }
      // no trailing barrier: next h1l writers are >=3 barriers away
    } // s loop
  } // work loop
}

// ============== launch ==============
extern "C" void kernel_launch(void* const* d_in, const int* in_sizes, int n_in,
                              void* d_out, int out_size, void* d_ws, size_t ws_size,
                              hipStream_t stream)
{
  const float* x    = (const float*)d_in[0];
  const unsigned char* ii = (const unsigned char*)d_in[1];
  const float* Wih0 = (const float*)d_in[2];
  const float* Whh0 = (const float*)d_in[3];
  const float* bih0 = (const float*)d_in[4];
  const float* bhh0 = (const float*)d_in[5];
  const float* Wih1 = (const float*)d_in[6];
  const float* Whh1 = (const float*)d_in[7];
  const float* bih1 = (const float*)d_in[8];
  const float* bhh1 = (const float*)d_in[9];
  float* out = (float*)d_out;
  char* ws = (char*)d_ws;

  int* ctrl = (int*)(ws + WS_CTRL);
  int* hist = (int*)(ws + WS_HIST);
  unsigned int* sorted = (unsigned int*)(ws + WS_SORT);
  float* bpk = (float*)(ws + WS_BIAS);
  unsigned short* wpkp = (unsigned short*)(ws + WS_WPK);

  hipMemsetAsync(d_ws, 0, 8192, stream);
  k_prep1 <<<1, 128, 0, stream>>>(ii, ctrl, hist);
  k_prep2 <<<1, 128, 0, stream>>>(ii, ctrl, hist, sorted);
  k_packw <<<Nn*TILES_PER_AGENT, 64, 0, stream>>>(Wih0, Whh0, Wih1, Whh1,
                                                  bih0, bhh0, bih1, bhh1, wpkp, bpk);
  k_main  <<<256, 512, 0, stream>>>(x, wpkp, bpk, sorted, ctrl, out);
}

// Round 10
// 1118.585 us; speedup vs baseline: 3.8779x; 1.0104x over previous
//
#include <hip/hip_runtime.h>
#include <stdint.h>

// Problem constants
#define Bb   128
#define Tt   256
#define Nn   4
#define Dd   64
#define Hh   256
#define G4H  1024          // 4*H
#define MR   64            // episode lanes (rows) per work item

// d_out layout: output (B,T,N,H) | h_n (B,N,L,H) | c_n (B,N,L,H)
#define OUT_HN 33554432    // 128*256*4*256
#define OUT_CN 33816576    // OUT_HN + 128*4*2*256

// workspace byte offsets
#define WS_CTRL 0          // 64 ints: [0]=stride mode, [1]=E, [2]=nchunks, [4..7]=work ctrs
#define WS_HIST 1024       // 257 ints
#define WS_SORT 8192       // 32768 u32 packed episodes (sorted desc by len)
#define WS_BIAS 139264     // N*2*1024 f32 packed bias
#define WS_WPK  262144     // packed bf16 weights: 4 agents * 1664 tiles * 1KB
#define TILES_PER_AGENT 1664   // 64 ntiles * (10 kb L0 + 16 kb L1)

typedef __attribute__((ext_vector_type(4))) float f32x4;
typedef __attribute__((ext_vector_type(8))) short bf16x8;

__device__ __forceinline__ unsigned short f2bf(float f){
  union { float f; unsigned u; } v; v.f = f;
  unsigned r = v.u + 0x7FFFu + ((v.u >> 16) & 1u);  // RNE
  return (unsigned short)(r >> 16);
}
__device__ __forceinline__ float bf2f(short s){
  union { unsigned u; float f; } v; v.u = ((unsigned)(unsigned short)s) << 16;
  return v.f;
}
// fast sigmoid / tanh via v_exp + v_rcp (absmax margin: 0.0039 vs 0.0231 threshold)
__device__ __forceinline__ float sigm(float x){
  return __builtin_amdgcn_rcpf(1.f + __expf(-x));
}
__device__ __forceinline__ float tanh_s(float x){
  return 1.f - 2.f * __builtin_amdgcn_rcpf(1.f + __expf(2.f * x));
}

// ---- LDS swizzle helpers (XOR bit4 with row&7 -> conflict-free b128 column reads) ----
__device__ __forceinline__ void st_h(unsigned short* hl, int row, int col, unsigned short v){
  int off = (row * (Hh*2) + col * 2) ^ ((row & 7) << 4);
  *(unsigned short*)((char*)hl + off) = v;
}
__device__ __forceinline__ bf16x8 ld_hfrag(const unsigned short* hl, int m, int kb, int l){
  int row = m*16 + (l & 15);
  int off = (row * (Hh*2) + kb*64 + ((l >> 4) << 4)) ^ ((row & 7) << 4);
  return *(const bf16x8*)((const char*)hl + off);
}
__device__ __forceinline__ bf16x8 ld_xfrag(const unsigned short* xl, int m, int kb, int l){
  int row = m*16 + (l & 15);
  int off = (row * (Dd*2) + kb*64 + ((l >> 4) << 4)) ^ ((row & 7) << 4);
  return *(const bf16x8*)((const char*)xl + off);
}

__device__ __forceinline__ bool get_flag(const unsigned char* p, int t, int stride){
  if (stride == 1) return p[t] != 0;
  return ((const int*)p)[t] != 0;   // covers int32 and f32 bit patterns
}

// ============== prep kernels (3 dispatches before k_main) ==============

__global__ void k_prep1(const unsigned char* ii, int* ctrl, int* hist){
  __shared__ int s_cnt;
  __shared__ int s_stride;
  int tid = threadIdx.x;          // 128 threads, one per b
  if (tid == 0) s_cnt = 0;
  __syncthreads();
  atomicAdd(&s_cnt, (ii[2*tid] != 0) + (ii[2*tid+1] != 0));
  __syncthreads();
  if (tid == 0){ s_stride = (s_cnt > 80) ? 1 : 4; ctrl[0] = s_stride; }
  __syncthreads();
  int stride = s_stride;
  const unsigned char* p = ii + (size_t)tid * Tt * stride;
  int start = 0;
  for (int t = 1; t < Tt; t++){
    if (get_flag(p, t, stride)){ atomicAdd(&hist[t - start], 1); start = t; }
  }
  atomicAdd(&hist[Tt - start], 1);
}

__global__ void k_prep2(const unsigned char* ii, int* ctrl, const int* hist,
                        unsigned int* sorted){
  __shared__ int offs_s[Tt + 1];
  int tid = threadIdx.x;          // 128 threads
  if (tid == 0){
    int run = 0;
    for (int len = Tt; len >= 1; len--){ offs_s[len] = run; run += hist[len]; }
    ctrl[1] = run;                     // E
    ctrl[2] = (run + MR - 1) / MR;     // nchunks
  }
  __syncthreads();
  int stride = ctrl[0];
  const unsigned char* p = ii + (size_t)tid * Tt * stride;
  int start = 0;
  for (int t = 1; t < Tt; t++){
    if (get_flag(p, t, stride)){
      int len = t - start;
      int pos = atomicAdd(&offs_s[len], 1);
      sorted[pos] = 0x80000000u | ((unsigned)tid << 16) | ((unsigned)start << 8) | (unsigned)(len - 1);
      start = t;
    }
  }
  int len = Tt - start;
  int pos = atomicAdd(&offs_s[len], 1);
  sorted[pos] = 0x80000000u | ((unsigned)tid << 16) | ((unsigned)start << 8) | (unsigned)(len - 1);
}

__global__ void k_packw(const float* __restrict__ Wih0, const float* __restrict__ Whh0,
                        const float* __restrict__ Wih1, const float* __restrict__ Whh1,
                        const float* __restrict__ bih0, const float* __restrict__ bhh0,
                        const float* __restrict__ bih1, const float* __restrict__ bhh1,
                        unsigned short* __restrict__ wpk, float* __restrict__ bpk){
  int bid = blockIdx.x;            // 0..6655
  int l = threadIdx.x;             // 0..63
  int n = bid / TILES_PER_AGENT;
  int r = bid % TILES_PER_AGENT;
  int layer, ntile, kb;
  if (r < 640){ layer = 0; ntile = r / 10; kb = r % 10; }
  else        { layer = 1; r -= 640; ntile = r / 16; kb = r % 16; }
  int col_sub = l >> 2;
  int k8      = (l & 3) * 8;
  int col  = ntile*16 + col_sub;
  int grow = (col & 3)*Hh + (col >> 2);
  const float* src;
  if (layer == 0){
    if (kb < 2) src = Wih0 + ((size_t)(n*G4H + grow))*Dd + kb*32 + k8;        // x part
    else        src = Whh0 + ((size_t)(n*G4H + grow))*Hh + (kb-2)*32 + k8;    // h0 part
  } else {
    if (kb < 8) src = Wih1 + ((size_t)(n*G4H + grow))*Hh + kb*32 + k8;        // h0_new part
    else        src = Whh1 + ((size_t)(n*G4H + grow))*Hh + (kb-8)*32 + k8;    // h1 part
  }
  int tl = (layer == 0) ? (ntile*10 + kb) : (640 + ntile*16 + kb);
  int lp = ((l & 3) << 4) | (l >> 2);
  unsigned short* dst = wpk + (((size_t)n*TILES_PER_AGENT + tl)*64 + lp)*8;
  #pragma unroll
  for (int j = 0; j < 8; j++) dst[j] = f2bf(src[j]);

  int id = bid*64 + l;
  if (id < Nn*2*G4H){
    int nb = id >> 11; int rb = id & 2047; int lyr = rb >> 10; int c = rb & 1023;
    int gr = (c & 3)*Hh + (c >> 2);
    float v = (lyr == 0) ? (bih0[nb*G4H + gr] + bhh0[nb*G4H + gr])
                         : (bih1[nb*G4H + gr] + bhh1[nb*G4H + gr]);
    bpk[id] = v;
  }
}

// ============== main kernel ==============
// 256 blocks x 512 threads, 1 block/CU ((512,1): 2 waves/SIMD -> 256-reg cap,
// proven spill-free in R9). Agent = blockIdx&3 (deterministic).
// BARRIER-CHAIN FIX (R9 was 78% idle, 5 barriers/step): h0l/h1l/xl are
// DOUBLE-BUFFERED -> nonlin writes go to buffer[nxt] while GEMM reads
// buffer[cur]; the write-after-read hazards that forced 5 barriers vanish.
// 2 barriers/step remain (h0_new visibility, h1_new+x visibility).
// Output-write(s-1) overlaps next step's L0 GEMM. All buffer rewrites are
// >=2 barriers after their last reader (verified per buffer & step parity).
__launch_bounds__(512, 1)
__global__ void k_main(const float* __restrict__ x_in,
                       const unsigned short* __restrict__ wpk,
                       const float* __restrict__ bpk,
                       const unsigned int* __restrict__ sorted,
                       int* __restrict__ ctrl,
                       float* __restrict__ out)
{
  __shared__ unsigned short h0l[2][MR*Hh];  // 2x32KB, swizzled bf16
  __shared__ unsigned short h1l[2][MR*Hh];  // 2x32KB
  __shared__ unsigned short xl [2][MR*Dd];  // 2x8KB
  __shared__ unsigned short biasl[2*G4H];   // 4KB bf16 packed bias
  __shared__ unsigned int epl[MR];
  __shared__ int item_s;

  const int tid = threadIdx.x;
  const int w   = tid >> 6;
  const int l   = tid & 63;
  const int n   = blockIdx.x & 3;           // deterministic agent assignment
  const int E       = ctrl[1];
  const int nchunks = ctrl[2];

  const unsigned short* wbase = wpk + (size_t)n * TILES_PER_AGENT * 64 * 8;

  for (int i = tid; i < 2*G4H; i += 512) biasl[i] = f2bf(bpk[n*2*G4H + i]);

  const int nrow = l & 15;   // lane's episode row within M-tile
  const int nul  = l >> 4;   // lane's unit_local 0..3

  while (true){
    __syncthreads();
    if (tid == 0) item_s = atomicAdd(&ctrl[4 + n], 1);
    __syncthreads();
    int chunk = item_s;
    if (chunk >= nchunks) break;

    if (tid < MR){
      int idx = chunk*MR + tid;
      epl[tid] = (idx < E) ? sorted[idx] : 0u;
    }
    // zero cur(=0) state buffers
    for (int i = tid; i < MR*Hh/4; i += 512){
      ((ushort4*)h0l[0])[i] = make_ushort4(0,0,0,0);
      ((ushort4*)h1l[0])[i] = make_ushort4(0,0,0,0);
    }
    __syncthreads();   // epl visible (needed for x staging below)

    unsigned int ep0 = epl[0];
    int maxlen = (ep0 >> 31) ? (int)(ep0 & 255) + 1 : 0;  // sorted desc -> lane0 is max

    // stage x(s=0) into xl[0]
    #pragma unroll
    for (int r2 = 0; r2 < 2; r2++){
      int row = r2*32 + (tid >> 4);
      int d4  = (tid & 15) * 4;
      unsigned int pk = epl[row];
      int len = (pk >> 31) ? (int)(pk & 255) + 1 : 0;
      ushort4 u = make_ushort4(0,0,0,0);
      if (0 < len){
        int b = (pk >> 16) & 127;
        int t = (int)((pk >> 8) & 255);
        const float* xp = x_in + (((size_t)b*Tt + t)*Nn + n)*Dd + d4;
        f32x4 v = *(const f32x4*)xp;
        u.x = f2bf(v[0]); u.y = f2bf(v[1]); u.z = f2bf(v[2]); u.w = f2bf(v[3]);
      }
      int off = (row*(Dd*2) + d4*2) ^ ((row & 7) << 4);
      *(ushort4*)((char*)xl[0] + off) = u;
    }
    __syncthreads();   // x0 + zeroed state visible

    float c0r[8][4], c1r[8][4];
    #pragma unroll
    for (int i = 0; i < 8; i++)
      #pragma unroll
      for (int m = 0; m < 4; m++){ c0r[i][m]=0.f; c1r[i][m]=0.f; }

    int cur = 0;
    #pragma unroll 1
    for (int s = 0; s < maxlen; s++){
      const int nxt = cur ^ 1;
      const unsigned short* h0c = h0l[cur];
      const unsigned short* h1c = h1l[cur];
      const unsigned short* xc  = xl[cur];
      unsigned short* h0n = h0l[nxt];
      unsigned short* h1n = h1l[nxt];

      // ---- P1a: output-write(s-1) from h1l[cur] (overlaps L0 GEMM) ----
      if (s > 0){
        #pragma unroll
        for (int r2 = 0; r2 < 2; r2++){
          int row = r2*32 + (tid >> 4);
          unsigned int pk = epl[row];
          int len = (pk >> 31) ? (int)(pk & 255) + 1 : 0;
          if (s-1 < len){
            int b = (pk >> 16) & 127;
            int t = (int)((pk >> 8) & 255) + (s-1);
            int l16 = tid & 15;
            int swz = (row & 7) << 4;
            float* op = out + (((size_t)b*Tt + t)*Nn + n)*Hh;
            #pragma unroll
            for (int k = 0; k < 4; k++){
              int off = (row*(Hh*2) + k*128 + l16*8) ^ swz;
              ushort4 u = *(const ushort4*)((const char*)h1c + off);
              f32x4 v = { bf2f((short)u.x), bf2f((short)u.y), bf2f((short)u.z), bf2f((short)u.w) };
              __builtin_nontemporal_store(v, (f32x4*)(op + k*64 + l16*4));
            }
          }
        }
      }

      // ---- P1b: LAYER 0 GEMM (reads xc, h0c) ----
      {
        f32x4 acc[8][4];
        #pragma unroll
        for (int i = 0; i < 8; i++){
          ushort4 bu = *(const ushort4*)&biasl[(w*8 + i)*16 + nul*4];
          f32x4 bv = { bf2f((short)bu.x), bf2f((short)bu.y),
                       bf2f((short)bu.z), bf2f((short)bu.w) };
          #pragma unroll
          for (int m = 0; m < 4; m++) acc[i][m] = bv;
        }
        #pragma unroll 1
        for (int kb = 0; kb < 10; kb++){
          bf16x8 a0, a1, a2, a3;
          if (kb < 2){
            a0 = ld_xfrag(xc, 0, kb, l); a1 = ld_xfrag(xc, 1, kb, l);
            a2 = ld_xfrag(xc, 2, kb, l); a3 = ld_xfrag(xc, 3, kb, l);
          } else {
            a0 = ld_hfrag(h0c, 0, kb-2, l); a1 = ld_hfrag(h0c, 1, kb-2, l);
            a2 = ld_hfrag(h0c, 2, kb-2, l); a3 = ld_hfrag(h0c, 3, kb-2, l);
          }
          #pragma unroll
          for (int i = 0; i < 8; i++){
            const bf16x8 bf = *(const bf16x8*)(wbase + (((size_t)((w*8+i)*10 + kb))*64 + l)*8);
            acc[i][0] = __builtin_amdgcn_mfma_f32_16x16x32_bf16(bf, a0, acc[i][0], 0, 0, 0);
            acc[i][1] = __builtin_amdgcn_mfma_f32_16x16x32_bf16(bf, a1, acc[i][1], 0, 0, 0);
            acc[i][2] = __builtin_amdgcn_mfma_f32_16x16x32_bf16(bf, a2, acc[i][2], 0, 0, 0);
            acc[i][3] = __builtin_amdgcn_mfma_f32_16x16x32_bf16(bf, a3, acc[i][3], 0, 0, 0);
          }
        }

        // L0 nonlin: writes h0l[nxt] — no conflict with readers of h0l[cur]
        #pragma unroll
        for (int i = 0; i < 8; i++){
          #pragma unroll
          for (int m = 0; m < 4; m++){
            f32x4 g = acc[i][m];
            float cn = sigm(g[1])*c0r[i][m] + sigm(g[0])*tanh_s(g[2]);
            float hn = sigm(g[3])*tanh_s(cn);
            c0r[i][m] = cn;
            int row  = m*16 + nrow;
            int unit = (w*8 + i)*4 + nul;
            st_h(h0n, row, unit, f2bf(hn));
            unsigned int pk = epl[row];
            if (pk >> 31){
              int len = (int)(pk & 255) + 1;
              int start = (pk >> 8) & 255;
              if (s == len - 1 && start + len == Tt){
                int b = (pk >> 16) & 127;
                size_t base = ((size_t)(b*Nn + n)*2 + 0)*Hh + unit;
                __builtin_nontemporal_store(hn, &out[OUT_HN + base]);
                __builtin_nontemporal_store(cn, &out[OUT_CN + base]);
              }
            }
          }
        }
      }
      __syncthreads();   // barrier alpha: h0_new visible

      // ---- P2a: stage x(s+1) into xl[nxt] (overlaps L1 GEMM) ----
      if (s + 1 < maxlen){
        #pragma unroll
        for (int r2 = 0; r2 < 2; r2++){
          int row = r2*32 + (tid >> 4);
          int d4  = (tid & 15) * 4;
          unsigned int pk = epl[row];
          int len = (pk >> 31) ? (int)(pk & 255) + 1 : 0;
          ushort4 u = make_ushort4(0,0,0,0);
          if (s + 1 < len){
            int b = (pk >> 16) & 127;
            int t = (int)((pk >> 8) & 255) + s + 1;
            const float* xp = x_in + (((size_t)b*Tt + t)*Nn + n)*Dd + d4;
            f32x4 v = *(const f32x4*)xp;
            u.x = f2bf(v[0]); u.y = f2bf(v[1]); u.z = f2bf(v[2]); u.w = f2bf(v[3]);
          }
          int off = (row*(Dd*2) + d4*2) ^ ((row & 7) << 4);
          *(ushort4*)((char*)xl[nxt] + off) = u;
        }
      }

      // ---- P2b: LAYER 1 GEMM (reads h0l[nxt], h1l[cur]) ----
      {
        f32x4 acc[8][4];
        #pragma unroll
        for (int i = 0; i < 8; i++){
          ushort4 bu = *(const ushort4*)&biasl[G4H + (w*8 + i)*16 + nul*4];
          f32x4 bv = { bf2f((short)bu.x), bf2f((short)bu.y),
                       bf2f((short)bu.z), bf2f((short)bu.w) };
          #pragma unroll
          for (int m = 0; m < 4; m++) acc[i][m] = bv;
        }
        #pragma unroll 1
        for (int kb = 0; kb < 16; kb++){
          bf16x8 a0, a1, a2, a3;
          if (kb < 8){
            a0 = ld_hfrag(h0n, 0, kb, l); a1 = ld_hfrag(h0n, 1, kb, l);
            a2 = ld_hfrag(h0n, 2, kb, l); a3 = ld_hfrag(h0n, 3, kb, l);
          } else {
            a0 = ld_hfrag(h1c, 0, kb-8, l); a1 = ld_hfrag(h1c, 1, kb-8, l);
            a2 = ld_hfrag(h1c, 2, kb-8, l); a3 = ld_hfrag(h1c, 3, kb-8, l);
          }
          #pragma unroll
          for (int i = 0; i < 8; i++){
            const bf16x8 bf = *(const bf16x8*)(wbase + (((size_t)(640 + (w*8+i)*16 + kb))*64 + l)*8);
            acc[i][0] = __builtin_amdgcn_mfma_f32_16x16x32_bf16(bf, a0, acc[i][0], 0, 0, 0);
            acc[i][1] = __builtin_amdgcn_mfma_f32_16x16x32_bf16(bf, a1, acc[i][1], 0, 0, 0);
            acc[i][2] = __builtin_amdgcn_mfma_f32_16x16x32_bf16(bf, a2, acc[i][2], 0, 0, 0);
            acc[i][3] = __builtin_amdgcn_mfma_f32_16x16x32_bf16(bf, a3, acc[i][3], 0, 0, 0);
          }
        }

        // L1 nonlin: writes h1l[nxt]
        #pragma unroll
        for (int i = 0; i < 8; i++){
          #pragma unroll
          for (int m = 0; m < 4; m++){
            f32x4 g = acc[i][m];
            float cn = sigm(g[1])*c1r[i][m] + sigm(g[0])*tanh_s(g[2]);
            float hn = sigm(g[3])*tanh_s(cn);
            c1r[i][m] = cn;
            int row  = m*16 + nrow;
            int unit = (w*8 + i)*4 + nul;
            st_h(h1n, row, unit, f2bf(hn));
            unsigned int pk = epl[row];
            if (pk >> 31){
              int len = (int)(pk & 255) + 1;
              int start = (pk >> 8) & 255;
              if (s == len - 1 && start + len == Tt){
                int b = (pk >> 16) & 127;
                size_t base = ((size_t)(b*Nn + n)*2 + 1)*Hh + unit;
                __builtin_nontemporal_store(hn, &out[OUT_HN + base]);
                __builtin_nontemporal_store(cn, &out[OUT_CN + base]);
              }
            }
          }
        }
      }
      __syncthreads();   // barrier beta: h1_new + x(s+1) visible
      cur = nxt;
    } // s loop

    // ---- epilogue: output-write for the last step from h1l[cur] ----
    if (maxlen > 0){
      int s = maxlen - 1;
      const unsigned short* h1c = h1l[cur];
      #pragma unroll
      for (int r2 = 0; r2 < 2; r2++){
        int row = r2*32 + (tid >> 4);
        unsigned int pk = epl[row];
        int len = (pk >> 31) ? (int)(pk & 255) + 1 : 0;
        if (s < len){
          int b = (pk >> 16) & 127;
          int t = (int)((pk >> 8) & 255) + s;
          int l16 = tid & 15;
          int swz = (row & 7) << 4;
          float* op = out + (((size_t)b*Tt + t)*Nn + n)*Hh;
          #pragma unroll
          for (int k = 0; k < 4; k++){
            int off = (row*(Hh*2) + k*128 + l16*8) ^ swz;
            ushort4 u = *(const ushort4*)((const char*)h1c + off);
            f32x4 v = { bf2f((short)u.x), bf2f((short)u.y), bf2f((short)u.z), bf2f((short)u.w) };
            __builtin_nontemporal_store(v, (f32x4*)(op + k*64 + l16*4));
          }
        }
      }
    }
  } // work loop
}

// ============== launch ==============
extern "C" void kernel_launch(void* const* d_in, const int* in_sizes, int n_in,
                              void* d_out, int out_size, void* d_ws, size_t ws_size,
                              hipStream_t stream)
{
  const float* x    = (const float*)d_in[0];
  const unsigned char* ii = (const unsigned char*)d_in[1];
  const float* Wih0 = (const float*)d_in[2];
  const float* Whh0 = (const float*)d_in[3];
  const float* bih0 = (const float*)d_in[4];
  const float* bhh0 = (const float*)d_in[5];
  const float* Wih1 = (const float*)d_in[6];
  const float* Whh1 = (const float*)d_in[7];
  const float* bih1 = (const float*)d_in[8];
  const float* bhh1 = (const float*)d_in[9];
  float* out = (float*)d_out;
  char* ws = (char*)d_ws;

  int* ctrl = (int*)(ws + WS_CTRL);
  int* hist = (int*)(ws + WS_HIST);
  unsigned int* sorted = (unsigned int*)(ws + WS_SORT);
  float* bpk = (float*)(ws + WS_BIAS);
  unsigned short* wpkp = (unsigned short*)(ws + WS_WPK);

  hipMemsetAsync(d_ws, 0, 8192, stream);
  k_prep1 <<<1, 128, 0, stream>>>(ii, ctrl, hist);
  k_prep2 <<<1, 128, 0, stream>>>(ii, ctrl, hist, sorted);
  k_packw <<<Nn*TILES_PER_AGENT, 64, 0, stream>>>(Wih0, Whh0, Wih1, Whh1,
                                                  bih0, bhh0, bih1, bhh1, wpkp, bpk);
  k_main  <<<256, 512, 0, stream>>>(x, wpkp, bpk, sorted, ctrl, out);
}